// Round 7
// baseline (477.405 us; speedup 1.0000x reference)
//
#include <hip/hip_runtime.h>
#include <hip/hip_bf16.h>

#define NN    50000
#define CC    4
#define NNZV  800000
#define TOTE  (CC * NNZV)          // 3,200,000 edges
#define NWG   1024                 // workgroups for hist/cscatter
#define EPW   (TOTE / NWG)         // 3125 edges per WG (exact)
#define NBKT  256                  // dst buckets (dst >> 8); 196 non-empty
#define NRB   782                  // ceil(50000/64) row blocks for dense stages

using bf16 = __hip_bfloat16;
typedef short short8 __attribute__((ext_vector_type(8)));
typedef float f32x4  __attribute__((ext_vector_type(4)));

__device__ __forceinline__ float bfu2f(unsigned short u) {
    union { unsigned int i; float f; } v;
    v.i = ((unsigned int)u) << 16;
    return v.f;
}
__device__ __forceinline__ float cvt(float x) { return x; }
__device__ __forceinline__ float cvt(bf16 x)  { return __bfloat162float(x); }
__device__ __forceinline__ unsigned short tobits(float x) {
    bf16 t = __float2bfloat16(x);
    return *(unsigned short*)&t;
}

// ---------------------------------------------------------------------------
// Kernel 0: runtime dtype detection (proven rounds 2-6).
// flags[0] = 1 if float inputs are f32; flags[1] = 1 if A is int64
// ---------------------------------------------------------------------------
__global__ void detect_kernel(const unsigned int* __restrict__ Xw,
                              const unsigned int* __restrict__ Aw,
                              int* __restrict__ flags) {
    __shared__ int cnt[2];
    const int t = threadIdx.x;
    if (t < 2) cnt[t] = 0;
    __syncthreads();
    int c1 = 0;
    for (int i = t; i < 1024; i += 256) {
        unsigned b = (Xw[i] >> 7) & 0xFF;
        if (b >= 118 && b <= 134) c1++;
    }
    atomicAdd(&cnt[0], c1);
    int c2 = 0;
    if (t < 128) c2 = (Aw[2 * t + 1] == 0) ? 1 : 0;
    atomicAdd(&cnt[1], c2);
    __syncthreads();
    if (t == 0) {
        flags[0] = (cnt[0] < 512) ? 1 : 0;
        flags[1] = (cnt[1] >= 96) ? 1 : 0;
    }
}

// ---------------------------------------------------------------------------
// pack_kernel: pre-pack B-operands into MFMA fragment order + f32 biases.
//   Wb  (l0): [k0<8][t8<8][lane<64][j<8]   <- W0[256][128]
//   Wb1 (l1): [k0<4][t4<4][lane<64][j<8]   <- W1[128][64]
//   Wbx (xw): [k0<2][tn<16][lane<64][j<8]  <- Ws[c][64][64], col=c*64+g
// ---------------------------------------------------------------------------
template<typename TF>
__device__ __forceinline__ void pack_body(const TF* __restrict__ W0, const TF* __restrict__ W1,
                                          const TF* __restrict__ Ws, const TF* __restrict__ b0,
                                          const TF* __restrict__ b1,
                                          unsigned short* __restrict__ Wb,
                                          unsigned short* __restrict__ Wb1,
                                          unsigned short* __restrict__ Wbx,
                                          float* __restrict__ bias0, float* __restrict__ bias1,
                                          int trip) {
    const int lane = trip & 63;
    const int q = lane >> 4, cI = lane & 15;
    if (trip < 4096) {
        const int k0 = trip >> 9, t8 = (trip >> 6) & 7;
        #pragma unroll
        for (int j = 0; j < 8; ++j)
            Wb[(size_t)trip * 8 + j] =
                tobits(cvt(W0[(size_t)(k0 * 32 + q * 8 + j) * 128 + t8 * 16 + cI]));
    } else if (trip < 5120) {
        const int u = trip - 4096;
        const int k0 = u >> 8, t4 = (u >> 6) & 3;
        #pragma unroll
        for (int j = 0; j < 8; ++j)
            Wb1[(size_t)u * 8 + j] =
                tobits(cvt(W1[(size_t)(k0 * 32 + q * 8 + j) * 64 + t4 * 16 + cI]));
    } else if (trip < 7168) {
        const int u = trip - 5120;
        const int k0 = u >> 10, tn = (u >> 6) & 15;
        const int col = tn * 16 + cI, c = col >> 6, g = col & 63;
        #pragma unroll
        for (int j = 0; j < 8; ++j)
            Wbx[(size_t)u * 8 + j] =
                tobits(cvt(Ws[((size_t)c * 64 + k0 * 32 + q * 8 + j) * 64 + g]));
    } else if (trip < 7296) {
        bias0[trip - 7168] = cvt(b0[trip - 7168]);
    } else if (trip < 7360) {
        bias1[trip - 7296] = cvt(b1[trip - 7296]);
    }
}

__global__ __launch_bounds__(256) void pack_kernel(const void* W0, const void* W1,
                                                   const void* Ws, const void* b0,
                                                   const void* b1,
                                                   unsigned short* Wb, unsigned short* Wb1,
                                                   unsigned short* Wbx,
                                                   float* bias0, float* bias1,
                                                   const int* __restrict__ flags) {
    const int trip = blockIdx.x * 256 + threadIdx.x;
    if (trip >= 7360) return;
    if (flags[0]) pack_body<float>((const float*)W0, (const float*)W1, (const float*)Ws,
                                   (const float*)b0, (const float*)b1, Wb, Wb1, Wbx, bias0, bias1, trip);
    else          pack_body<bf16> ((const bf16*)W0, (const bf16*)W1, (const bf16*)Ws,
                                   (const bf16*)b0, (const bf16*)b1, Wb, Wb1, Wbx, bias0, bias1, trip);
}

// ---------------------------------------------------------------------------
// xw_mfma: XW[c][n][g] = X @ Ws[c].  M=50000 K=64 N=256. 64-row tiles.
// ---------------------------------------------------------------------------
template<typename TF>
__device__ __forceinline__ void xw_stage(const TF* __restrict__ X, unsigned short* Xs,
                                         int n0, int t) {
    #pragma unroll
    for (int i = 0; i < 4; ++i) {
        const int r = (t >> 4) + i * 16;
        const int k = (t & 15) * 4;
        const int row = n0 + r;
        ushort4 o = make_ushort4(0, 0, 0, 0);
        if (row < NN) {
            o.x = tobits(cvt(X[(size_t)row * 64 + k + 0]));
            o.y = tobits(cvt(X[(size_t)row * 64 + k + 1]));
            o.z = tobits(cvt(X[(size_t)row * 64 + k + 2]));
            o.w = tobits(cvt(X[(size_t)row * 64 + k + 3]));
        }
        *(ushort4*)(&Xs[r * 80 + k]) = o;
    }
}

__global__ __launch_bounds__(256) void xw_mfma(const void* __restrict__ X,
                                               const unsigned short* __restrict__ Wbx,
                                               unsigned short* __restrict__ XW,
                                               const int* __restrict__ flags) {
    __shared__ unsigned short Xs[64 * 80];
    const int t = threadIdx.x, n0 = blockIdx.x * 64;
    if (flags[0]) xw_stage<float>((const float*)X, Xs, n0, t);
    else          xw_stage<bf16> ((const bf16*)X,  Xs, n0, t);
    __syncthreads();
    const int w = t >> 6, lane = t & 63;
    const int q = lane >> 4, cI = lane & 15;
    f32x4 acc[16];
    #pragma unroll
    for (int i = 0; i < 16; ++i) acc[i] = (f32x4){0.f, 0.f, 0.f, 0.f};
    const unsigned short* arow = &Xs[(w * 16 + cI) * 80 + q * 8];
    #pragma unroll
    for (int k0 = 0; k0 < 2; ++k0) {
        short8 a = *(const short8*)(arow + k0 * 32);
        #pragma unroll
        for (int tn = 0; tn < 16; ++tn) {
            short8 b = *(const short8*)(Wbx + ((size_t)(k0 * 16 + tn) * 64 + lane) * 8);
            acc[tn] = __builtin_amdgcn_mfma_f32_16x16x32_bf16(a, b, acc[tn], 0, 0, 0);
        }
    }
    const int rbase = n0 + w * 16 + q * 4;
    #pragma unroll
    for (int tn = 0; tn < 16; ++tn) {
        const int col = tn * 16 + cI, c = col >> 6, g = col & 63;
        #pragma unroll
        for (int r = 0; r < 4; ++r) {
            const int row = rbase + r;
            if (row < NN) XW[((size_t)c * NN + row) * 64 + g] = tobits(acc[tn][r]);
        }
    }
}

// ---------------------------------------------------------------------------
// CSR build, bucketed: hist -> scan -> cscatter -> dfinal (proven rounds 4-6)
// ---------------------------------------------------------------------------
template<typename TI>
__device__ __forceinline__ void hist_body(const TI* __restrict__ A,
                                          unsigned int* __restrict__ hist,
                                          unsigned int* lh) {
    const int w = blockIdx.x, t = threadIdx.x;
    lh[t] = 0;
    __syncthreads();
    const int base = w * EPW;
    for (int i = t; i < EPW; i += 256) {
        const int e  = base + i;
        const int c  = e / NNZV;
        const int ei = e - c * NNZV;
        const int dst = (int)A[(size_t)(c * 2) * NNZV + ei];
        if ((unsigned)dst < NN) atomicAdd(&lh[dst >> 8], 1u);
    }
    __syncthreads();
    hist[(size_t)t * NWG + w] = lh[t];
}

__global__ __launch_bounds__(256) void hist_kernel(const void* __restrict__ A,
                                                   unsigned int* __restrict__ hist,
                                                   const int* __restrict__ flags) {
    __shared__ unsigned int lh[NBKT];
    if (flags[1]) hist_body<long long>((const long long*)A, hist, lh);
    else          hist_body<int>      ((const int*)A,       hist, lh);
}

__global__ __launch_bounds__(256) void scan1_kernel(const unsigned int* __restrict__ in,
                                                    unsigned int* __restrict__ out,
                                                    unsigned int* __restrict__ bsums) {
    __shared__ unsigned int ts[256];
    const int t = threadIdx.x;
    const int base = blockIdx.x * 1024 + t * 4;
    uint4 v = *(const uint4*)(in + base);
    unsigned int s = v.x + v.y + v.z + v.w;
    ts[t] = s;
    __syncthreads();
    for (int off = 1; off < 256; off <<= 1) {
        unsigned int val = (t >= off) ? ts[t - off] : 0;
        __syncthreads();
        ts[t] += val;
        __syncthreads();
    }
    unsigned int ex = ts[t] - s;
    uint4 o;
    o.x = ex; o.y = ex + v.x; o.z = ex + v.x + v.y; o.w = ex + v.x + v.y + v.z;
    *(uint4*)(out + base) = o;
    if (t == 255) bsums[blockIdx.x] = ts[255];
}

__global__ __launch_bounds__(256) void scan2_kernel(const unsigned int* __restrict__ bsums,
                                                    unsigned int* __restrict__ bscan) {
    __shared__ unsigned int ts[256];
    const int t = threadIdx.x;
    unsigned int s = bsums[t];
    ts[t] = s;
    __syncthreads();
    for (int off = 1; off < 256; off <<= 1) {
        unsigned int val = (t >= off) ? ts[t - off] : 0;
        __syncthreads();
        ts[t] += val;
        __syncthreads();
    }
    bscan[t] = ts[t] - s;
}

__global__ __launch_bounds__(256) void scan3_kernel(unsigned int* __restrict__ out,
                                                    const unsigned int* __restrict__ bscan) {
    const int base = blockIdx.x * 1024 + threadIdx.x * 4;
    const unsigned int add = bscan[blockIdx.x];
    uint4 v = *(uint4*)(out + base);
    v.x += add; v.y += add; v.z += add; v.w += add;
    *(uint4*)(out + base) = v;
}

template<typename TI>
__device__ __forceinline__ void cscat_body(const TI* __restrict__ A,
                                           const unsigned int* __restrict__ cpos,
                                           unsigned int* __restrict__ recs,
                                           unsigned int* cur) {
    const int w = blockIdx.x, t = threadIdx.x;
    cur[t] = cpos[(size_t)t * NWG + w];
    __syncthreads();
    const int base = w * EPW;
    for (int i = t; i < EPW; i += 256) {
        const int e  = base + i;
        const int c  = e / NNZV;
        const int ei = e - c * NNZV;
        const int dst = (int)A[(size_t)(c * 2 + 0) * NNZV + ei];
        const int src = (int)A[(size_t)(c * 2 + 1) * NNZV + ei];
        if ((unsigned)dst >= NN || (unsigned)src >= NN) continue;
        const unsigned int pos = atomicAdd(&cur[dst >> 8], 1u);
        recs[pos] = ((unsigned)(dst & 255) << 18) | ((unsigned)c << 16) | (unsigned)src;
    }
}

__global__ __launch_bounds__(256) void cscatter_kernel(const void* __restrict__ A,
                                                       const unsigned int* __restrict__ cpos,
                                                       unsigned int* __restrict__ recs,
                                                       const int* __restrict__ flags) {
    __shared__ unsigned int cur[NBKT];
    if (flags[1]) cscat_body<long long>((const long long*)A, cpos, recs, cur);
    else          cscat_body<int>      ((const int*)A,       cpos, recs, cur);
}

__global__ __launch_bounds__(256) void dfinal_kernel(const unsigned int* __restrict__ cpos,
                                                     const unsigned int* __restrict__ recs,
                                                     unsigned short* __restrict__ edge_src,
                                                     int* __restrict__ offs,
                                                     int* __restrict__ cnt) {
    __shared__ unsigned int scnt[1024], soff[1024];
    __shared__ unsigned int ts[256];
    const int b = blockIdx.x, t = threadIdx.x;
    const unsigned int base = cpos[(size_t)b * NWG];
    const unsigned int next = cpos[(size_t)(b + 1) * NWG];
    const int n = (int)(next - base);
    for (int j = t; j < 1024; j += 256) scnt[j] = 0;
    __syncthreads();
    for (int i = t; i < n; i += 256) {
        const unsigned int r = recs[base + i];
        const int seg = (int)(((r >> 18) & 255u) * 4u + ((r >> 16) & 3u));
        atomicAdd(&scnt[seg], 1u);
    }
    __syncthreads();
    {
        const int j0 = t * 4;
        unsigned int v0 = scnt[j0], v1 = scnt[j0 + 1], v2 = scnt[j0 + 2], v3 = scnt[j0 + 3];
        unsigned int s = v0 + v1 + v2 + v3;
        ts[t] = s;
        __syncthreads();
        for (int off = 1; off < 256; off <<= 1) {
            unsigned int val = (t >= off) ? ts[t - off] : 0;
            __syncthreads();
            ts[t] += val;
            __syncthreads();
        }
        unsigned int ex = ts[t] - s;
        soff[j0] = ex; soff[j0 + 1] = ex + v0;
        soff[j0 + 2] = ex + v0 + v1; soff[j0 + 3] = ex + v0 + v1 + v2;
    }
    __syncthreads();
    for (int j = t; j < 1024; j += 256) {
        const int dst = b * 256 + (j >> 2);
        if (dst < NN) {
            offs[b * 1024 + j] = (int)(base + soff[j]);
            cnt [b * 1024 + j] = (int)scnt[j];
        }
    }
    __syncthreads();
    for (int i = t; i < n; i += 256) {
        const unsigned int r = recs[base + i];
        const int seg = (int)(((r >> 18) & 255u) * 4u + ((r >> 16) & 3u));
        const unsigned int pos = atomicAdd(&soff[seg], 1u);
        edge_src[base + pos] = (unsigned short)(r & 0xFFFFu);
    }
}

// ---------------------------------------------------------------------------
// gather: 8 L2-resident passes folded into one launch.
// pass = blockIdx&7 -> (c, g-half). Per pass the read table is
// XW_c[:, half*32..+32] = 3.2 MB < 4 MiB L2. With round-robin block->XCD
// mapping each XCD works one pass -> its table slice is L2-resident, no
// cross-XCD duplication. Wave layout: 4 edge-subgroups x 16 lanes x ushort2.
// ---------------------------------------------------------------------------
__global__ __launch_bounds__(256) void gather_kernel(const unsigned short* __restrict__ edge_src,
                                                     const int* __restrict__ offs,
                                                     const int* __restrict__ cnt,
                                                     const unsigned short* __restrict__ XW,
                                                     unsigned short* __restrict__ H) {
    const int t    = threadIdx.x;
    const int pass = blockIdx.x & 7;
    const int dgrp = blockIdx.x >> 3;
    const int c    = pass >> 1;
    const int half = pass & 1;
    const int w    = t >> 6;
    const int lane = t & 63;
    const int k    = lane >> 4;          // edge subgroup 0..3
    const int g2   = (lane & 15) * 2;    // column pair within half
    const int dst  = dgrp * 4 + w;       // 12500*4 = 50000 exact
    const int seg  = dst * 4 + c;
    const int beg  = offs[seg];
    const int n    = cnt[seg];
    const unsigned short* ep  = edge_src + beg;
    const unsigned short* xwc = XW + (size_t)c * NN * 64 + half * 32 + g2;
    float a0 = 0.f, a1 = 0.f;
    for (int e0 = 0; e0 < n; e0 += 8) {
        const int ea = e0 + k;
        const int eb = e0 + 4 + k;
        if (ea < n) {
            const ushort2 v = *(const ushort2*)(xwc + (size_t)ep[ea] * 64);
            a0 += bfu2f(v.x); a1 += bfu2f(v.y);
        }
        if (eb < n) {
            const ushort2 v = *(const ushort2*)(xwc + (size_t)ep[eb] * 64);
            a0 += bfu2f(v.x); a1 += bfu2f(v.y);
        }
    }
    a0 += __shfl_xor(a0, 16, 64); a0 += __shfl_xor(a0, 32, 64);
    a1 += __shfl_xor(a1, 16, 64); a1 += __shfl_xor(a1, 32, 64);
    if (k == 0) {
        ushort2 o;
        o.x = tobits(a0); o.y = tobits(a1);
        *(ushort2*)(H + (size_t)dst * 256 + c * 64 + half * 32 + g2) = o;
    }
}

// ---------------------------------------------------------------------------
// l0_mfma: h = H @ W0 + b0 (M=50000 K=256 N=128) + fused BN partial sums.
// ---------------------------------------------------------------------------
__global__ __launch_bounds__(256) void l0_mfma(const unsigned short* __restrict__ Hg,
                                               const unsigned short* __restrict__ Wb,
                                               const float* __restrict__ bias0,
                                               unsigned short* __restrict__ hO,
                                               float* __restrict__ stats) {
    __shared__ unsigned short Hs[64 * 264];
    __shared__ float psum[128], psq[128];
    const int t = threadIdx.x;
    const int n0 = blockIdx.x * 64;
    #pragma unroll
    for (int i = 0; i < 16; ++i) {
        const int r = (t >> 6) + i * 4;
        const int k = (t & 63) * 4;
        const int row = n0 + r;
        ushort4 v = make_ushort4(0, 0, 0, 0);
        if (row < NN) v = *(const ushort4*)(Hg + (size_t)row * 256 + k);
        *(ushort4*)(&Hs[r * 264 + k]) = v;
    }
    if (t < 128) { psum[t] = 0.f; psq[t] = 0.f; }
    __syncthreads();
    const int w = t >> 6, lane = t & 63;
    const int q = lane >> 4, cI = lane & 15;
    f32x4 acc[8];
    #pragma unroll
    for (int i = 0; i < 8; ++i) acc[i] = (f32x4){0.f, 0.f, 0.f, 0.f};
    const unsigned short* arow = &Hs[(w * 16 + cI) * 264 + q * 8];
    #pragma unroll
    for (int k0 = 0; k0 < 8; ++k0) {
        short8 a = *(const short8*)(arow + k0 * 32);
        #pragma unroll
        for (int t8 = 0; t8 < 8; ++t8) {
            short8 b = *(const short8*)(Wb + ((size_t)(k0 * 8 + t8) * 64 + lane) * 8);
            acc[t8] = __builtin_amdgcn_mfma_f32_16x16x32_bf16(a, b, acc[t8], 0, 0, 0);
        }
    }
    const int rbase = n0 + w * 16 + q * 4;
    #pragma unroll
    for (int t8 = 0; t8 < 8; ++t8) {
        const int col = t8 * 16 + cI;
        const float bc = bias0[col];
        float s = 0.f, qq = 0.f;
        #pragma unroll
        for (int r = 0; r < 4; ++r) {
            const int row = rbase + r;
            float v = acc[t8][r] + bc;
            if (row < NN) hO[(size_t)row * 128 + col] = tobits(v);
            else          v = 0.f;
            s += v; qq += v * v;
        }
        s  += __shfl_xor(s, 16, 64);  s  += __shfl_xor(s, 32, 64);
        qq += __shfl_xor(qq, 16, 64); qq += __shfl_xor(qq, 32, 64);
        if (q == 0) { atomicAdd(&psum[col], s); atomicAdd(&psq[col], qq); }
    }
    __syncthreads();
    if (t < 128) { atomicAdd(&stats[t], psum[t]); atomicAdd(&stats[128 + t], psq[t]); }
}

// ---------------------------------------------------------------------------
// bn: fold stats into per-column affine
// ---------------------------------------------------------------------------
template<typename TF>
__device__ __forceinline__ void bn_body(const float* __restrict__ stats,
                                        const TF* __restrict__ gamma,
                                        const TF* __restrict__ beta,
                                        float* __restrict__ coef) {
    const int j = threadIdx.x;
    const float invN = 1.0f / (float)NN;
    const float mean = stats[j] * invN;
    const float var  = stats[128 + j] * invN - mean * mean;
    const float inv  = rsqrtf(var + 1e-5f);
    const float a = cvt(gamma[j]) * inv;
    const float b = cvt(beta[j]) - mean * a;
    coef[j] = a;
    coef[128 + j] = b;
}

__global__ void bn_kernel(const float* __restrict__ stats,
                          const void* __restrict__ gamma,
                          const void* __restrict__ beta,
                          float* __restrict__ coef,
                          const int* __restrict__ flags) {
    if (flags[0]) bn_body<float>(stats, (const float*)gamma, (const float*)beta, coef);
    else          bn_body<bf16> (stats, (const bf16*)gamma,  (const bf16*)beta,  coef);
}

// ---------------------------------------------------------------------------
// l1_mfma: out = elu(bn(h)) @ W1 + b1  (M=50000 K=128 N=64)
// ---------------------------------------------------------------------------
__global__ __launch_bounds__(256) void l1_mfma(const unsigned short* __restrict__ hg,
                                               const float* __restrict__ coef,
                                               const unsigned short* __restrict__ Wb1,
                                               const float* __restrict__ bias1,
                                               void* __restrict__ outv,
                                               const int* __restrict__ flags) {
    __shared__ unsigned short Es[64 * 136];
    const int t = threadIdx.x;
    const int n0 = blockIdx.x * 64;
    #pragma unroll
    for (int i = 0; i < 8; ++i) {
        const int r = (t >> 5) + i * 8;
        const int k = (t & 31) * 4;
        const int row = n0 + r;
        ushort4 o = make_ushort4(0, 0, 0, 0);
        if (row < NN) {
            ushort4 v = *(const ushort4*)(hg + (size_t)row * 128 + k);
            float f0 = coef[k + 0] * bfu2f(v.x) + coef[128 + k + 0];
            float f1 = coef[k + 1] * bfu2f(v.y) + coef[128 + k + 1];
            float f2 = coef[k + 2] * bfu2f(v.z) + coef[128 + k + 2];
            float f3 = coef[k + 3] * bfu2f(v.w) + coef[128 + k + 3];
            f0 = f0 > 0.f ? f0 : expm1f(f0);
            f1 = f1 > 0.f ? f1 : expm1f(f1);
            f2 = f2 > 0.f ? f2 : expm1f(f2);
            f3 = f3 > 0.f ? f3 : expm1f(f3);
            o.x = tobits(f0); o.y = tobits(f1); o.z = tobits(f2); o.w = tobits(f3);
        }
        *(ushort4*)(&Es[r * 136 + k]) = o;
    }
    __syncthreads();
    const int w = t >> 6, lane = t & 63;
    const int q = lane >> 4, cI = lane & 15;
    f32x4 acc[4];
    #pragma unroll
    for (int i = 0; i < 4; ++i) acc[i] = (f32x4){0.f, 0.f, 0.f, 0.f};
    const unsigned short* arow = &Es[(w * 16 + cI) * 136 + q * 8];
    #pragma unroll
    for (int k0 = 0; k0 < 4; ++k0) {
        short8 a = *(const short8*)(arow + k0 * 32);
        #pragma unroll
        for (int t4 = 0; t4 < 4; ++t4) {
            short8 b = *(const short8*)(Wb1 + ((size_t)(k0 * 4 + t4) * 64 + lane) * 8);
            acc[t4] = __builtin_amdgcn_mfma_f32_16x16x32_bf16(a, b, acc[t4], 0, 0, 0);
        }
    }
    const int rbase = n0 + w * 16 + q * 4;
    const int f32out = flags[0];
    #pragma unroll
    for (int t4 = 0; t4 < 4; ++t4) {
        const int col = t4 * 16 + cI;
        const float bc = bias1[col];
        #pragma unroll
        for (int r = 0; r < 4; ++r) {
            const int row = rbase + r;
            if (row < NN) {
                const float v = acc[t4][r] + bc;
                if (f32out) ((float*)outv)[(size_t)row * 64 + col] = v;
                else        ((unsigned short*)outv)[(size_t)row * 64 + col] = tobits(v);
            }
        }
    }
}

// ---------------------------------------------------------------------------
// Workspace layout (bytes): unchanged from round 5/6 (~83.0 MiB)
// ---------------------------------------------------------------------------
extern "C" void kernel_launch(void* const* d_in, const int* in_sizes, int n_in,
                              void* d_out, int out_size, void* d_ws, size_t ws_size,
                              hipStream_t stream) {
    const void* A     = d_in[0];
    const void* X     = d_in[1];
    const void* Ws    = d_in[2];
    const void* W0    = d_in[3];
    const void* b0    = d_in[4];
    const void* gamma = d_in[5];
    const void* beta  = d_in[6];
    const void* W1    = d_in[7];
    const void* b1    = d_in[8];

    char* ws = (char*)d_ws;
    unsigned short* XW       = (unsigned short*)(ws);
    unsigned short* H        = (unsigned short*)(ws + 25600000);
    unsigned short* h        = (unsigned short*)(ws + 51200000);
    unsigned int*   recs     = (unsigned int*)  (ws + 64000000);
    unsigned int*   hist     = (unsigned int*)  (ws + 76800000);
    unsigned int*   cpos     = (unsigned int*)  (ws + 77848576);
    unsigned int*   bsums    = (unsigned int*)  (ws + 78897152);
    unsigned int*   bscan    = (unsigned int*)  (ws + 78898176);
    int*            offs     = (int*)           (ws + 78899200);
    int*            cnt      = (int*)           (ws + 79699200);
    unsigned short* edge_src = (unsigned short*)(ws + 80499200);
    float*          stats    = (float*)         (ws + 86899200);
    float*          coef     = (float*)         (ws + 86900224);
    int*            flags    = (int*)           (ws + 86901248);
    unsigned short* Wb       = (unsigned short*)(ws + 86901504);
    unsigned short* Wb1      = (unsigned short*)(ws + 86967040);
    unsigned short* Wbx      = (unsigned short*)(ws + 86983424);
    float*          bias0    = (float*)         (ws + 87016192);
    float*          bias1    = (float*)         (ws + 87016704);

    detect_kernel<<<1, 256, 0, stream>>>((const unsigned int*)X, (const unsigned int*)A, flags);
    hipMemsetAsync(stats, 0, 1024, stream);

    pack_kernel   <<<29, 256, 0, stream>>>(W0, W1, Ws, b0, b1, Wb, Wb1, Wbx, bias0, bias1, flags);
    xw_mfma       <<<NRB, 256, 0, stream>>>(X, Wbx, XW, flags);
    hist_kernel   <<<NWG, 256, 0, stream>>>(A, hist, flags);
    scan1_kernel  <<<256, 256, 0, stream>>>(hist, cpos, bsums);
    scan2_kernel  <<<1, 256, 0, stream>>>(bsums, bscan);
    scan3_kernel  <<<256, 256, 0, stream>>>(cpos, bscan);
    cscatter_kernel<<<NWG, 256, 0, stream>>>(A, cpos, recs, flags);
    dfinal_kernel <<<196, 256, 0, stream>>>(cpos, recs, edge_src, offs, cnt);
    gather_kernel <<<12500 * 8, 256, 0, stream>>>(edge_src, offs, cnt, XW, H);
    l0_mfma       <<<NRB, 256, 0, stream>>>(H, Wb, bias0, h, stats);
    bn_kernel     <<<1, 128, 0, stream>>>(stats, gamma, beta, coef, flags);
    l1_mfma       <<<NRB, 256, 0, stream>>>(h, coef, Wb1, bias1, d_out, flags);
}

// Round 8
// 319.201 us; speedup vs baseline: 1.4956x; 1.4956x over previous
//
#include <hip/hip_runtime.h>
#include <hip/hip_bf16.h>

#define NN    50000
#define CC    4
#define NNZV  800000
#define TOTE  (CC * NNZV)          // 3,200,000 edges
#define NWG   1024                 // workgroups for cscatter
#define EPW   (TOTE / NWG)         // 3125 edges per WG (exact)
#define NBKT  256                  // dst buckets (dst >> 8); 196 non-empty
#define RCAP  18432                // records per bucket region (mean 16384 + 16 sigma)
#define NRB   782                  // ceil(50000/64) row blocks for dense stages

using bf16 = __hip_bfloat16;
typedef short short8 __attribute__((ext_vector_type(8)));
typedef float f32x4  __attribute__((ext_vector_type(4)));

__device__ __forceinline__ float bfu2f(unsigned short u) {
    union { unsigned int i; float f; } v;
    v.i = ((unsigned int)u) << 16;
    return v.f;
}
__device__ __forceinline__ float cvt(float x) { return x; }
__device__ __forceinline__ float cvt(bf16 x)  { return __bfloat162float(x); }
__device__ __forceinline__ unsigned short tobits(float x) {
    bf16 t = __float2bfloat16(x);
    return *(unsigned short*)&t;
}

// ---------------------------------------------------------------------------
// Kernel 0: runtime dtype detection (proven rounds 2-7).
// flags[0] = 1 if float inputs are f32; flags[1] = 1 if A is int64
// ---------------------------------------------------------------------------
__global__ void detect_kernel(const unsigned int* __restrict__ Xw,
                              const unsigned int* __restrict__ Aw,
                              int* __restrict__ flags) {
    __shared__ int cnt[2];
    const int t = threadIdx.x;
    if (t < 2) cnt[t] = 0;
    __syncthreads();
    int c1 = 0;
    for (int i = t; i < 1024; i += 256) {
        unsigned b = (Xw[i] >> 7) & 0xFF;
        if (b >= 118 && b <= 134) c1++;
    }
    atomicAdd(&cnt[0], c1);
    int c2 = 0;
    if (t < 128) c2 = (Aw[2 * t + 1] == 0) ? 1 : 0;
    atomicAdd(&cnt[1], c2);
    __syncthreads();
    if (t == 0) {
        flags[0] = (cnt[0] < 512) ? 1 : 0;
        flags[1] = (cnt[1] >= 96) ? 1 : 0;
    }
}

// ---------------------------------------------------------------------------
// pack_kernel: pre-pack B-operands into MFMA fragment order + f32 biases.
//   Wb  (l0): [k0<8][t8<8][lane<64][j<8]   <- W0[256][128]
//   Wb1 (l1): [k0<4][t4<4][lane<64][j<8]   <- W1[128][64]
//   Wbx (xw): [k0<2][tn<16][lane<64][j<8]  <- Ws[c][64][64], col=c*64+g
// ---------------------------------------------------------------------------
template<typename TF>
__device__ __forceinline__ void pack_body(const TF* __restrict__ W0, const TF* __restrict__ W1,
                                          const TF* __restrict__ Ws, const TF* __restrict__ b0,
                                          const TF* __restrict__ b1,
                                          unsigned short* __restrict__ Wb,
                                          unsigned short* __restrict__ Wb1,
                                          unsigned short* __restrict__ Wbx,
                                          float* __restrict__ bias0, float* __restrict__ bias1,
                                          int trip) {
    const int lane = trip & 63;
    const int q = lane >> 4, cI = lane & 15;
    if (trip < 4096) {
        const int k0 = trip >> 9, t8 = (trip >> 6) & 7;
        #pragma unroll
        for (int j = 0; j < 8; ++j)
            Wb[(size_t)trip * 8 + j] =
                tobits(cvt(W0[(size_t)(k0 * 32 + q * 8 + j) * 128 + t8 * 16 + cI]));
    } else if (trip < 5120) {
        const int u = trip - 4096;
        const int k0 = u >> 8, t4 = (u >> 6) & 3;
        #pragma unroll
        for (int j = 0; j < 8; ++j)
            Wb1[(size_t)u * 8 + j] =
                tobits(cvt(W1[(size_t)(k0 * 32 + q * 8 + j) * 64 + t4 * 16 + cI]));
    } else if (trip < 7168) {
        const int u = trip - 5120;
        const int k0 = u >> 10, tn = (u >> 6) & 15;
        const int col = tn * 16 + cI, c = col >> 6, g = col & 63;
        #pragma unroll
        for (int j = 0; j < 8; ++j)
            Wbx[(size_t)u * 8 + j] =
                tobits(cvt(Ws[((size_t)c * 64 + k0 * 32 + q * 8 + j) * 64 + g]));
    } else if (trip < 7296) {
        bias0[trip - 7168] = cvt(b0[trip - 7168]);
    } else if (trip < 7360) {
        bias1[trip - 7296] = cvt(b1[trip - 7296]);
    }
}

__global__ __launch_bounds__(256) void pack_kernel(const void* W0, const void* W1,
                                                   const void* Ws, const void* b0,
                                                   const void* b1,
                                                   unsigned short* Wb, unsigned short* Wb1,
                                                   unsigned short* Wbx,
                                                   float* bias0, float* bias1,
                                                   const int* __restrict__ flags) {
    const int trip = blockIdx.x * 256 + threadIdx.x;
    if (trip >= 7360) return;
    if (flags[0]) pack_body<float>((const float*)W0, (const float*)W1, (const float*)Ws,
                                   (const float*)b0, (const float*)b1, Wb, Wb1, Wbx, bias0, bias1, trip);
    else          pack_body<bf16> ((const bf16*)W0, (const bf16*)W1, (const bf16*)Ws,
                                   (const bf16*)b0, (const bf16*)b1, Wb, Wb1, Wbx, bias0, bias1, trip);
}

// ---------------------------------------------------------------------------
// xw_mfma: XW[c][n][g] = X @ Ws[c].  M=50000 K=64 N=256. 64-row tiles.
// ---------------------------------------------------------------------------
template<typename TF>
__device__ __forceinline__ void xw_stage(const TF* __restrict__ X, unsigned short* Xs,
                                         int n0, int t) {
    #pragma unroll
    for (int i = 0; i < 4; ++i) {
        const int r = (t >> 4) + i * 16;
        const int k = (t & 15) * 4;
        const int row = n0 + r;
        ushort4 o = make_ushort4(0, 0, 0, 0);
        if (row < NN) {
            o.x = tobits(cvt(X[(size_t)row * 64 + k + 0]));
            o.y = tobits(cvt(X[(size_t)row * 64 + k + 1]));
            o.z = tobits(cvt(X[(size_t)row * 64 + k + 2]));
            o.w = tobits(cvt(X[(size_t)row * 64 + k + 3]));
        }
        *(ushort4*)(&Xs[r * 80 + k]) = o;
    }
}

__global__ __launch_bounds__(256) void xw_mfma(const void* __restrict__ X,
                                               const unsigned short* __restrict__ Wbx,
                                               unsigned short* __restrict__ XW,
                                               const int* __restrict__ flags) {
    __shared__ unsigned short Xs[64 * 80];
    const int t = threadIdx.x, n0 = blockIdx.x * 64;
    if (flags[0]) xw_stage<float>((const float*)X, Xs, n0, t);
    else          xw_stage<bf16> ((const bf16*)X,  Xs, n0, t);
    __syncthreads();
    const int w = t >> 6, lane = t & 63;
    const int q = lane >> 4, cI = lane & 15;
    f32x4 acc[16];
    #pragma unroll
    for (int i = 0; i < 16; ++i) acc[i] = (f32x4){0.f, 0.f, 0.f, 0.f};
    const unsigned short* arow = &Xs[(w * 16 + cI) * 80 + q * 8];
    #pragma unroll
    for (int k0 = 0; k0 < 2; ++k0) {
        short8 a = *(const short8*)(arow + k0 * 32);
        #pragma unroll
        for (int tn = 0; tn < 16; ++tn) {
            short8 b = *(const short8*)(Wbx + ((size_t)(k0 * 16 + tn) * 64 + lane) * 8);
            acc[tn] = __builtin_amdgcn_mfma_f32_16x16x32_bf16(a, b, acc[tn], 0, 0, 0);
        }
    }
    const int rbase = n0 + w * 16 + q * 4;
    #pragma unroll
    for (int tn = 0; tn < 16; ++tn) {
        const int col = tn * 16 + cI, c = col >> 6, g = col & 63;
        #pragma unroll
        for (int r = 0; r < 4; ++r) {
            const int row = rbase + r;
            if (row < NN) XW[((size_t)c * NN + row) * 64 + g] = tobits(acc[tn][r]);
        }
    }
}

// ---------------------------------------------------------------------------
// cscatter2: single pass over A. Per WG: LDS-buffer the 3125 records + LDS
// bucket histogram; reserve a slice per bucket with ONE global atomicAdd;
// scatter records into fixed-capacity bucket regions recs[b*RCAP ..].
// Replaces hist + scan1 + scan3 + old cscatter.
// ---------------------------------------------------------------------------
template<typename TI>
__device__ __forceinline__ void cscat2_body(const TI* __restrict__ A,
                                            unsigned int* __restrict__ gcur,
                                            unsigned int* __restrict__ recs,
                                            unsigned int* lh, unsigned int* lrec) {
    const int w = blockIdx.x, t = threadIdx.x;
    lh[t] = 0;
    __syncthreads();
    const int base = w * EPW;
    for (int i = t; i < EPW; i += 256) {
        const int e  = base + i;
        const int c  = e / NNZV;
        const int ei = e - c * NNZV;
        const int dst = (int)A[(size_t)(c * 2 + 0) * NNZV + ei];
        const int src = (int)A[(size_t)(c * 2 + 1) * NNZV + ei];
        unsigned int rec = 0xFFFFFFFFu;
        if ((unsigned)dst < NN && (unsigned)src < NN) {
            rec = ((unsigned)dst << 16) | (unsigned)src;
            atomicAdd(&lh[dst >> 8], 1u);
        }
        lrec[i] = rec;
    }
    __syncthreads();
    const unsigned int myslice = atomicAdd(&gcur[t], lh[t]);
    __syncthreads();
    lh[t] = myslice;           // lh becomes the per-bucket write cursor
    __syncthreads();
    for (int i = t; i < EPW; i += 256) {
        const unsigned int rec = lrec[i];
        if (rec == 0xFFFFFFFFu) continue;
        const int e   = base + i;
        const int c   = e / NNZV;
        const int dst = (int)(rec >> 16);
        const int src = (int)(rec & 0xFFFFu);
        const int b   = dst >> 8;
        const unsigned int pos = atomicAdd(&lh[b], 1u);
        if (pos < RCAP)
            recs[(size_t)b * RCAP + pos] =
                ((unsigned)(dst & 255) << 18) | ((unsigned)c << 16) | (unsigned)src;
    }
}

__global__ __launch_bounds__(256) void cscatter2_kernel(const void* __restrict__ A,
                                                        unsigned int* __restrict__ gcur,
                                                        unsigned int* __restrict__ recs,
                                                        const int* __restrict__ flags) {
    __shared__ unsigned int lh[NBKT];
    __shared__ unsigned int lrec[EPW];
    if (flags[1]) cscat2_body<long long>((const long long*)A, gcur, recs, lh, lrec);
    else          cscat2_body<int>      ((const int*)A,       gcur, recs, lh, lrec);
}

// bscan: single block, exclusive scan of final bucket counts -> ebase
__global__ __launch_bounds__(256) void bscan_kernel(const unsigned int* __restrict__ gcur,
                                                    unsigned int* __restrict__ ebase) {
    __shared__ unsigned int ts[256];
    const int t = threadIdx.x;
    unsigned int s = gcur[t];
    ts[t] = s;
    __syncthreads();
    for (int off = 1; off < 256; off <<= 1) {
        unsigned int val = (t >= off) ? ts[t - off] : 0;
        __syncthreads();
        ts[t] += val;
        __syncthreads();
    }
    ebase[t] = ts[t] - s;
}

// dfinal: one WG per bucket. LDS seg counts -> LDS scan -> offs/cnt + final
// contiguous edge_src. seg_local = (dst&255)*4 + c.
__global__ __launch_bounds__(256) void dfinal_kernel(const unsigned int* __restrict__ gcur,
                                                     const unsigned int* __restrict__ ebase,
                                                     const unsigned int* __restrict__ recs,
                                                     unsigned short* __restrict__ edge_src,
                                                     int* __restrict__ offs,
                                                     int* __restrict__ cnt) {
    __shared__ unsigned int scnt[1024], soff[1024];
    __shared__ unsigned int ts[256];
    const int b = blockIdx.x, t = threadIdx.x;
    const unsigned int obase = ebase[b];
    int n = (int)gcur[b];
    if (n > RCAP) n = RCAP;
    const size_t rbase = (size_t)b * RCAP;
    for (int j = t; j < 1024; j += 256) scnt[j] = 0;
    __syncthreads();
    for (int i = t; i < n; i += 256) {
        const unsigned int r = recs[rbase + i];
        const int seg = (int)(((r >> 18) & 255u) * 4u + ((r >> 16) & 3u));
        atomicAdd(&scnt[seg], 1u);
    }
    __syncthreads();
    {
        const int j0 = t * 4;
        unsigned int v0 = scnt[j0], v1 = scnt[j0 + 1], v2 = scnt[j0 + 2], v3 = scnt[j0 + 3];
        unsigned int s = v0 + v1 + v2 + v3;
        ts[t] = s;
        __syncthreads();
        for (int off = 1; off < 256; off <<= 1) {
            unsigned int val = (t >= off) ? ts[t - off] : 0;
            __syncthreads();
            ts[t] += val;
            __syncthreads();
        }
        unsigned int ex = ts[t] - s;
        soff[j0] = ex; soff[j0 + 1] = ex + v0;
        soff[j0 + 2] = ex + v0 + v1; soff[j0 + 3] = ex + v0 + v1 + v2;
    }
    __syncthreads();
    for (int j = t; j < 1024; j += 256) {
        const int dst = b * 256 + (j >> 2);
        if (dst < NN) {
            offs[b * 1024 + j] = (int)(obase + soff[j]);
            cnt [b * 1024 + j] = (int)scnt[j];
        }
    }
    __syncthreads();
    for (int i = t; i < n; i += 256) {
        const unsigned int r = recs[rbase + i];
        const int seg = (int)(((r >> 18) & 255u) * 4u + ((r >> 16) & 3u));
        const unsigned int pos = atomicAdd(&soff[seg], 1u);
        edge_src[obase + pos] = (unsigned short)(r & 0xFFFFu);
    }
}

// ---------------------------------------------------------------------------
// gather: block = 4 dsts (grid 12500); wave c handles its category for all 4.
// Per-dst setup (offs/cnt/edge-list latency) amortized 4x; interior 8-edge
// chunks unchecked. Wave layout: 4 edge-subgroups x 16 lanes x ushort4.
// ---------------------------------------------------------------------------
__global__ __launch_bounds__(256) void gather_kernel(const unsigned short* __restrict__ edge_src,
                                                     const int* __restrict__ offs,
                                                     const int* __restrict__ cnt,
                                                     const unsigned short* __restrict__ XW,
                                                     unsigned short* __restrict__ H) {
    const int t    = threadIdx.x;
    const int c    = t >> 6;
    const int lane = t & 63;
    const int k    = lane >> 4;        // edge subgroup 0..3
    const int g4   = (lane & 15) * 4;  // this lane's 4 g-columns
    const int d0   = blockIdx.x * 4;
    const unsigned short* xwc = XW + (size_t)c * NN * 64;
    #pragma unroll
    for (int dd = 0; dd < 4; ++dd) {
        const int dst = d0 + dd;
        const int seg = dst * 4 + c;
        const int beg = offs[seg];
        const int n   = cnt[seg];
        const unsigned short* ep = edge_src + beg;
        float a0 = 0.f, a1 = 0.f, a2 = 0.f, a3 = 0.f;
        int e0 = 0;
        for (; e0 + 8 <= n; e0 += 8) {
            const int sa = ep[e0 + k];
            const int sb = ep[e0 + 4 + k];
            const ushort4 va = *(const ushort4*)(xwc + (size_t)sa * 64 + g4);
            const ushort4 vb = *(const ushort4*)(xwc + (size_t)sb * 64 + g4);
            a0 += bfu2f(va.x) + bfu2f(vb.x);
            a1 += bfu2f(va.y) + bfu2f(vb.y);
            a2 += bfu2f(va.z) + bfu2f(vb.z);
            a3 += bfu2f(va.w) + bfu2f(vb.w);
        }
        {
            const int ea = e0 + k;
            const int eb = e0 + 4 + k;
            if (ea < n) {
                const ushort4 v = *(const ushort4*)(xwc + (size_t)ep[ea] * 64 + g4);
                a0 += bfu2f(v.x); a1 += bfu2f(v.y); a2 += bfu2f(v.z); a3 += bfu2f(v.w);
            }
            if (eb < n) {
                const ushort4 v = *(const ushort4*)(xwc + (size_t)ep[eb] * 64 + g4);
                a0 += bfu2f(v.x); a1 += bfu2f(v.y); a2 += bfu2f(v.z); a3 += bfu2f(v.w);
            }
        }
        a0 += __shfl_xor(a0, 16, 64); a0 += __shfl_xor(a0, 32, 64);
        a1 += __shfl_xor(a1, 16, 64); a1 += __shfl_xor(a1, 32, 64);
        a2 += __shfl_xor(a2, 16, 64); a2 += __shfl_xor(a2, 32, 64);
        a3 += __shfl_xor(a3, 16, 64); a3 += __shfl_xor(a3, 32, 64);
        if (k == 0) {
            ushort4 o;
            o.x = tobits(a0); o.y = tobits(a1); o.z = tobits(a2); o.w = tobits(a3);
            *(ushort4*)(H + (size_t)dst * 256 + c * 64 + g4) = o;
        }
    }
}

// ---------------------------------------------------------------------------
// l0_mfma: h = H @ W0 + b0 (M=50000 K=256 N=128) + fused BN partial sums.
// ---------------------------------------------------------------------------
__global__ __launch_bounds__(256) void l0_mfma(const unsigned short* __restrict__ Hg,
                                               const unsigned short* __restrict__ Wb,
                                               const float* __restrict__ bias0,
                                               unsigned short* __restrict__ hO,
                                               float* __restrict__ stats) {
    __shared__ unsigned short Hs[64 * 264];
    __shared__ float psum[128], psq[128];
    const int t = threadIdx.x;
    const int n0 = blockIdx.x * 64;
    #pragma unroll
    for (int i = 0; i < 16; ++i) {
        const int r = (t >> 6) + i * 4;
        const int k = (t & 63) * 4;
        const int row = n0 + r;
        ushort4 v = make_ushort4(0, 0, 0, 0);
        if (row < NN) v = *(const ushort4*)(Hg + (size_t)row * 256 + k);
        *(ushort4*)(&Hs[r * 264 + k]) = v;
    }
    if (t < 128) { psum[t] = 0.f; psq[t] = 0.f; }
    __syncthreads();
    const int w = t >> 6, lane = t & 63;
    const int q = lane >> 4, cI = lane & 15;
    f32x4 acc[8];
    #pragma unroll
    for (int i = 0; i < 8; ++i) acc[i] = (f32x4){0.f, 0.f, 0.f, 0.f};
    const unsigned short* arow = &Hs[(w * 16 + cI) * 264 + q * 8];
    #pragma unroll
    for (int k0 = 0; k0 < 8; ++k0) {
        short8 a = *(const short8*)(arow + k0 * 32);
        #pragma unroll
        for (int t8 = 0; t8 < 8; ++t8) {
            short8 b = *(const short8*)(Wb + ((size_t)(k0 * 8 + t8) * 64 + lane) * 8);
            acc[t8] = __builtin_amdgcn_mfma_f32_16x16x32_bf16(a, b, acc[t8], 0, 0, 0);
        }
    }
    const int rbase = n0 + w * 16 + q * 4;
    #pragma unroll
    for (int t8 = 0; t8 < 8; ++t8) {
        const int col = t8 * 16 + cI;
        const float bc = bias0[col];
        float s = 0.f, qq = 0.f;
        #pragma unroll
        for (int r = 0; r < 4; ++r) {
            const int row = rbase + r;
            float v = acc[t8][r] + bc;
            if (row < NN) hO[(size_t)row * 128 + col] = tobits(v);
            else          v = 0.f;
            s += v; qq += v * v;
        }
        s  += __shfl_xor(s, 16, 64);  s  += __shfl_xor(s, 32, 64);
        qq += __shfl_xor(qq, 16, 64); qq += __shfl_xor(qq, 32, 64);
        if (q == 0) { atomicAdd(&psum[col], s); atomicAdd(&psq[col], qq); }
    }
    __syncthreads();
    if (t < 128) { atomicAdd(&stats[t], psum[t]); atomicAdd(&stats[128 + t], psq[t]); }
}

// ---------------------------------------------------------------------------
// bn: fold stats into per-column affine
// ---------------------------------------------------------------------------
template<typename TF>
__device__ __forceinline__ void bn_body(const float* __restrict__ stats,
                                        const TF* __restrict__ gamma,
                                        const TF* __restrict__ beta,
                                        float* __restrict__ coef) {
    const int j = threadIdx.x;
    const float invN = 1.0f / (float)NN;
    const float mean = stats[j] * invN;
    const float var  = stats[128 + j] * invN - mean * mean;
    const float inv  = rsqrtf(var + 1e-5f);
    const float a = cvt(gamma[j]) * inv;
    const float b = cvt(beta[j]) - mean * a;
    coef[j] = a;
    coef[128 + j] = b;
}

__global__ void bn_kernel(const float* __restrict__ stats,
                          const void* __restrict__ gamma,
                          const void* __restrict__ beta,
                          float* __restrict__ coef,
                          const int* __restrict__ flags) {
    if (flags[0]) bn_body<float>(stats, (const float*)gamma, (const float*)beta, coef);
    else          bn_body<bf16> (stats, (const bf16*)gamma,  (const bf16*)beta,  coef);
}

// ---------------------------------------------------------------------------
// l1_mfma: out = elu(bn(h)) @ W1 + b1  (M=50000 K=128 N=64)
// ---------------------------------------------------------------------------
__global__ __launch_bounds__(256) void l1_mfma(const unsigned short* __restrict__ hg,
                                               const float* __restrict__ coef,
                                               const unsigned short* __restrict__ Wb1,
                                               const float* __restrict__ bias1,
                                               void* __restrict__ outv,
                                               const int* __restrict__ flags) {
    __shared__ unsigned short Es[64 * 136];
    const int t = threadIdx.x;
    const int n0 = blockIdx.x * 64;
    #pragma unroll
    for (int i = 0; i < 8; ++i) {
        const int r = (t >> 5) + i * 8;
        const int k = (t & 31) * 4;
        const int row = n0 + r;
        ushort4 o = make_ushort4(0, 0, 0, 0);
        if (row < NN) {
            ushort4 v = *(const ushort4*)(hg + (size_t)row * 128 + k);
            float f0 = coef[k + 0] * bfu2f(v.x) + coef[128 + k + 0];
            float f1 = coef[k + 1] * bfu2f(v.y) + coef[128 + k + 1];
            float f2 = coef[k + 2] * bfu2f(v.z) + coef[128 + k + 2];
            float f3 = coef[k + 3] * bfu2f(v.w) + coef[128 + k + 3];
            f0 = f0 > 0.f ? f0 : expm1f(f0);
            f1 = f1 > 0.f ? f1 : expm1f(f1);
            f2 = f2 > 0.f ? f2 : expm1f(f2);
            f3 = f3 > 0.f ? f3 : expm1f(f3);
            o.x = tobits(f0); o.y = tobits(f1); o.z = tobits(f2); o.w = tobits(f3);
        }
        *(ushort4*)(&Es[r * 136 + k]) = o;
    }
    __syncthreads();
    const int w = t >> 6, lane = t & 63;
    const int q = lane >> 4, cI = lane & 15;
    f32x4 acc[4];
    #pragma unroll
    for (int i = 0; i < 4; ++i) acc[i] = (f32x4){0.f, 0.f, 0.f, 0.f};
    const unsigned short* arow = &Es[(w * 16 + cI) * 136 + q * 8];
    #pragma unroll
    for (int k0 = 0; k0 < 4; ++k0) {
        short8 a = *(const short8*)(arow + k0 * 32);
        #pragma unroll
        for (int t4 = 0; t4 < 4; ++t4) {
            short8 b = *(const short8*)(Wb1 + ((size_t)(k0 * 4 + t4) * 64 + lane) * 8);
            acc[t4] = __builtin_amdgcn_mfma_f32_16x16x32_bf16(a, b, acc[t4], 0, 0, 0);
        }
    }
    const int rbase = n0 + w * 16 + q * 4;
    const int f32out = flags[0];
    #pragma unroll
    for (int t4 = 0; t4 < 4; ++t4) {
        const int col = t4 * 16 + cI;
        const float bc = bias1[col];
        #pragma unroll
        for (int r = 0; r < 4; ++r) {
            const int row = rbase + r;
            if (row < NN) {
                const float v = acc[t4][r] + bc;
                if (f32out) ((float*)outv)[(size_t)row * 64 + col] = v;
                else        ((unsigned short*)outv)[(size_t)row * 64 + col] = tobits(v);
            }
        }
    }
}

// ---------------------------------------------------------------------------
// Workspace layout (bytes):
//   XW       : [C,N,64] bf16   @ 0            25,600,000
//   H        : [N,256]  bf16   @ 25,600,000   25,600,000
//   h        : [N,128]  bf16   @ 51,200,000   12,800,000
//   recs     : [196*RCAP] u32  @ 64,000,000   14,450,688
//   ebase    : [256] u32       @ 78,450,688       1,024
//   offs     : [200000] i32    @ 78,451,712     800,000
//   cnt      : [200000] i32    @ 79,251,712     800,000
//   edge_src : [3.2M] u16      @ 80,051,712   6,400,000
//   stats    : [256] f32       @ 86,451,712       1,024   -- memset w/ gcur
//   gcur     : [256] u32       @ 86,452,736       1,024
//   coef     : [256] f32       @ 86,453,760       1,024
//   flags    : [2] i32         @ 86,454,784         256
//   Wb       : u16             @ 86,455,040      65,536
//   Wb1      : u16             @ 86,520,576      16,384
//   Wbx      : u16             @ 86,536,960      32,768
//   bias0    : f32[128]        @ 86,569,728         512
//   bias1    : f32[64]         @ 86,570,240         256
// total 86,570,496 B (~82.6 MiB, <= round-7 footprint)
// ---------------------------------------------------------------------------
extern "C" void kernel_launch(void* const* d_in, const int* in_sizes, int n_in,
                              void* d_out, int out_size, void* d_ws, size_t ws_size,
                              hipStream_t stream) {
    const void* A     = d_in[0];
    const void* X     = d_in[1];
    const void* Ws    = d_in[2];
    const void* W0    = d_in[3];
    const void* b0    = d_in[4];
    const void* gamma = d_in[5];
    const void* beta  = d_in[6];
    const void* W1    = d_in[7];
    const void* b1    = d_in[8];

    char* ws = (char*)d_ws;
    unsigned short* XW       = (unsigned short*)(ws);
    unsigned short* H        = (unsigned short*)(ws + 25600000);
    unsigned short* h        = (unsigned short*)(ws + 51200000);
    unsigned int*   recs     = (unsigned int*)  (ws + 64000000);
    unsigned int*   ebase    = (unsigned int*)  (ws + 78450688);
    int*            offs     = (int*)           (ws + 78451712);
    int*            cnt      = (int*)           (ws + 79251712);
    unsigned short* edge_src = (unsigned short*)(ws + 80051712);
    float*          stats    = (float*)         (ws + 86451712);
    unsigned int*   gcur     = (unsigned int*)  (ws + 86452736);
    float*          coef     = (float*)         (ws + 86453760);
    int*            flags    = (int*)           (ws + 86454784);
    unsigned short* Wb       = (unsigned short*)(ws + 86455040);
    unsigned short* Wb1      = (unsigned short*)(ws + 86520576);
    unsigned short* Wbx      = (unsigned short*)(ws + 86536960);
    float*          bias0    = (float*)         (ws + 86569728);
    float*          bias1    = (float*)         (ws + 86570240);

    detect_kernel<<<1, 256, 0, stream>>>((const unsigned int*)X, (const unsigned int*)A, flags);
    hipMemsetAsync(stats, 0, 2048, stream);   // zero stats + gcur every call

    pack_kernel    <<<29, 256, 0, stream>>>(W0, W1, Ws, b0, b1, Wb, Wb1, Wbx, bias0, bias1, flags);
    xw_mfma        <<<NRB, 256, 0, stream>>>(X, Wbx, XW, flags);
    cscatter2_kernel<<<NWG, 256, 0, stream>>>(A, gcur, recs, flags);
    bscan_kernel   <<<1, 256, 0, stream>>>(gcur, ebase);
    dfinal_kernel  <<<196, 256, 0, stream>>>(gcur, ebase, recs, edge_src, offs, cnt);
    gather_kernel  <<<12500, 256, 0, stream>>>(edge_src, offs, cnt, XW, H);
    l0_mfma        <<<NRB, 256, 0, stream>>>(H, Wb, bias0, h, stats);
    bn_kernel      <<<1, 128, 0, stream>>>(stats, gamma, beta, coef, flags);
    l1_mfma        <<<NRB, 256, 0, stream>>>(h, coef, Wb1, bias1, d_out, flags);
}

// Round 9
// 305.862 us; speedup vs baseline: 1.5609x; 1.0436x over previous
//
#include <hip/hip_runtime.h>
#include <hip/hip_bf16.h>

#define NN    50000
#define CC    4
#define NNZV  800000
#define TOTE  (CC * NNZV)          // 3,200,000 edges
#define NWG   1024                 // workgroups for cscatter
#define EPW   (TOTE / NWG)         // 3125 edges per WG (exact)
#define NBKT  256                  // dst buckets (dst >> 8); 196 non-empty
#define RCAP  18432                // records per bucket region
#define NRB   782                  // ceil(50000/64) row blocks for dense stages

using bf16 = __hip_bfloat16;
typedef short short8 __attribute__((ext_vector_type(8)));
typedef float f32x4  __attribute__((ext_vector_type(4)));

__device__ __forceinline__ float bfu2f(unsigned short u) {
    union { unsigned int i; float f; } v;
    v.i = ((unsigned int)u) << 16;
    return v.f;
}
__device__ __forceinline__ float cvt(float x) { return x; }
__device__ __forceinline__ float cvt(bf16 x)  { return __bfloat162float(x); }
__device__ __forceinline__ unsigned short tobits(float x) {
    bf16 t = __float2bfloat16(x);
    return *(unsigned short*)&t;
}

// vectorized 4-element staging load -> packed bf16 bits
__device__ __forceinline__ ushort4 load4bits(const float* X, size_t idx) {
    const float4 v = *(const float4*)(X + idx);
    ushort4 o;
    o.x = tobits(v.x); o.y = tobits(v.y); o.z = tobits(v.z); o.w = tobits(v.w);
    return o;
}
__device__ __forceinline__ ushort4 load4bits(const bf16* X, size_t idx) {
    return *(const ushort4*)((const unsigned short*)X + idx);
}

// ---------------------------------------------------------------------------
// Kernel 0: runtime dtype detection (proven rounds 2-8).
// ---------------------------------------------------------------------------
__global__ void detect_kernel(const unsigned int* __restrict__ Xw,
                              const unsigned int* __restrict__ Aw,
                              int* __restrict__ flags) {
    __shared__ int cnt[2];
    const int t = threadIdx.x;
    if (t < 2) cnt[t] = 0;
    __syncthreads();
    int c1 = 0;
    for (int i = t; i < 1024; i += 256) {
        unsigned b = (Xw[i] >> 7) & 0xFF;
        if (b >= 118 && b <= 134) c1++;
    }
    atomicAdd(&cnt[0], c1);
    int c2 = 0;
    if (t < 128) c2 = (Aw[2 * t + 1] == 0) ? 1 : 0;
    atomicAdd(&cnt[1], c2);
    __syncthreads();
    if (t == 0) {
        flags[0] = (cnt[0] < 512) ? 1 : 0;
        flags[1] = (cnt[1] >= 96) ? 1 : 0;
    }
}

// ---------------------------------------------------------------------------
// pack_kernel: pre-pack B-operands into MFMA fragment order + f32 biases.
// ---------------------------------------------------------------------------
template<typename TF>
__device__ __forceinline__ void pack_body(const TF* __restrict__ W0, const TF* __restrict__ W1,
                                          const TF* __restrict__ Ws, const TF* __restrict__ b0,
                                          const TF* __restrict__ b1,
                                          unsigned short* __restrict__ Wb,
                                          unsigned short* __restrict__ Wb1,
                                          unsigned short* __restrict__ Wbx,
                                          float* __restrict__ bias0, float* __restrict__ bias1,
                                          int trip) {
    const int lane = trip & 63;
    const int q = lane >> 4, cI = lane & 15;
    if (trip < 4096) {
        const int k0 = trip >> 9, t8 = (trip >> 6) & 7;
        #pragma unroll
        for (int j = 0; j < 8; ++j)
            Wb[(size_t)trip * 8 + j] =
                tobits(cvt(W0[(size_t)(k0 * 32 + q * 8 + j) * 128 + t8 * 16 + cI]));
    } else if (trip < 5120) {
        const int u = trip - 4096;
        const int k0 = u >> 8, t4 = (u >> 6) & 3;
        #pragma unroll
        for (int j = 0; j < 8; ++j)
            Wb1[(size_t)u * 8 + j] =
                tobits(cvt(W1[(size_t)(k0 * 32 + q * 8 + j) * 64 + t4 * 16 + cI]));
    } else if (trip < 7168) {
        const int u = trip - 5120;
        const int k0 = u >> 10, tn = (u >> 6) & 15;
        const int col = tn * 16 + cI, c = col >> 6, g = col & 63;
        #pragma unroll
        for (int j = 0; j < 8; ++j)
            Wbx[(size_t)u * 8 + j] =
                tobits(cvt(Ws[((size_t)c * 64 + k0 * 32 + q * 8 + j) * 64 + g]));
    } else if (trip < 7296) {
        bias0[trip - 7168] = cvt(b0[trip - 7168]);
    } else if (trip < 7360) {
        bias1[trip - 7296] = cvt(b1[trip - 7296]);
    }
}

__global__ __launch_bounds__(256) void pack_kernel(const void* W0, const void* W1,
                                                   const void* Ws, const void* b0,
                                                   const void* b1,
                                                   unsigned short* Wb, unsigned short* Wb1,
                                                   unsigned short* Wbx,
                                                   float* bias0, float* bias1,
                                                   const int* __restrict__ flags) {
    const int trip = blockIdx.x * 256 + threadIdx.x;
    if (trip >= 7360) return;
    if (flags[0]) pack_body<float>((const float*)W0, (const float*)W1, (const float*)Ws,
                                   (const float*)b0, (const float*)b1, Wb, Wb1, Wbx, bias0, bias1, trip);
    else          pack_body<bf16> ((const bf16*)W0, (const bf16*)W1, (const bf16*)Ws,
                                   (const bf16*)b0, (const bf16*)b1, Wb, Wb1, Wbx, bias0, bias1, trip);
}

// ---------------------------------------------------------------------------
// xw_mfma: XW[c][n][g] = X @ Ws[c].  M=50000 K=64 N=256. 64-row tiles.
// Epilogue: LDS-transposed tile -> coalesced ushort8 stores.
// ---------------------------------------------------------------------------
template<typename TF>
__device__ __forceinline__ void xw_stage(const TF* __restrict__ X, unsigned short* Xs,
                                         int n0, int t) {
    #pragma unroll
    for (int i = 0; i < 4; ++i) {
        const int r = (t >> 4) + i * 16;
        const int k = (t & 15) * 4;
        const int row = n0 + r;
        ushort4 o = make_ushort4(0, 0, 0, 0);
        if (row < NN) o = load4bits(X, (size_t)row * 64 + k);
        *(ushort4*)(&Xs[r * 80 + k]) = o;
    }
}

__global__ __launch_bounds__(256) void xw_mfma(const void* __restrict__ X,
                                               const unsigned short* __restrict__ Wbx,
                                               unsigned short* __restrict__ XW,
                                               const int* __restrict__ flags) {
    __shared__ unsigned short Xs[64 * 264];   // staged X (stride 80), then out tile (stride 264)
    const int t = threadIdx.x, n0 = blockIdx.x * 64;
    if (flags[0]) xw_stage<float>((const float*)X, Xs, n0, t);
    else          xw_stage<bf16> ((const bf16*)X,  Xs, n0, t);
    __syncthreads();
    const int w = t >> 6, lane = t & 63;
    const int q = lane >> 4, cI = lane & 15;
    f32x4 acc[16];
    #pragma unroll
    for (int i = 0; i < 16; ++i) acc[i] = (f32x4){0.f, 0.f, 0.f, 0.f};
    const unsigned short* arow = &Xs[(w * 16 + cI) * 80 + q * 8];
    short8 a0 = *(const short8*)(arow);
    short8 a1 = *(const short8*)(arow + 32);
    #pragma unroll
    for (int tn = 0; tn < 16; ++tn) {
        short8 b = *(const short8*)(Wbx + ((size_t)tn * 64 + lane) * 8);
        acc[tn] = __builtin_amdgcn_mfma_f32_16x16x32_bf16(a0, b, acc[tn], 0, 0, 0);
    }
    #pragma unroll
    for (int tn = 0; tn < 16; ++tn) {
        short8 b = *(const short8*)(Wbx + ((size_t)(16 + tn) * 64 + lane) * 8);
        acc[tn] = __builtin_amdgcn_mfma_f32_16x16x32_bf16(a1, b, acc[tn], 0, 0, 0);
    }
    __syncthreads();   // done reading Xs as input
    const int rloc = w * 16 + q * 4;
    #pragma unroll
    for (int tn = 0; tn < 16; ++tn) {
        const int col = tn * 16 + cI;
        #pragma unroll
        for (int r = 0; r < 4; ++r)
            Xs[(rloc + r) * 264 + col] = tobits(acc[tn][r]);
    }
    __syncthreads();
    // store: 64 rows x 256 cols bf16; chunk = 8 cols; 2048 chunks / 256 thr = 8 each
    #pragma unroll
    for (int i = 0; i < 8; ++i) {
        const int m    = t + i * 256;
        const int row  = m >> 5;
        const int col0 = (m & 31) * 8;
        const int c    = col0 >> 6, g = col0 & 63;
        const int grow = n0 + row;
        if (grow < NN)
            *(ushort4*)(XW + ((size_t)c * NN + grow) * 64 + g + 0) = *(ushort4*)(&Xs[row * 264 + col0]);
        // 8 shorts = two ushort4? use one 16B store:
    }
    // (ushort4 covers 8 B; do the second half)
    #pragma unroll
    for (int i = 0; i < 8; ++i) {
        const int m    = t + i * 256;
        const int row  = m >> 5;
        const int col0 = (m & 31) * 8 + 4;
        const int c    = (col0 - 4) >> 6, g = ((col0 - 4) & 63) + 4;
        const int grow = n0 + row;
        if (grow < NN)
            *(ushort4*)(XW + ((size_t)c * NN + grow) * 64 + g) = *(ushort4*)(&Xs[row * 264 + col0]);
    }
}

// ---------------------------------------------------------------------------
// cscatter2: single pass over A -> bucketed records (proven round 8).
// ---------------------------------------------------------------------------
template<typename TI>
__device__ __forceinline__ void cscat2_body(const TI* __restrict__ A,
                                            unsigned int* __restrict__ gcur,
                                            unsigned int* __restrict__ recs,
                                            unsigned int* lh, unsigned int* lrec) {
    const int w = blockIdx.x, t = threadIdx.x;
    lh[t] = 0;
    __syncthreads();
    const int base = w * EPW;
    for (int i = t; i < EPW; i += 256) {
        const int e  = base + i;
        const int c  = e / NNZV;
        const int ei = e - c * NNZV;
        const int dst = (int)A[(size_t)(c * 2 + 0) * NNZV + ei];
        const int src = (int)A[(size_t)(c * 2 + 1) * NNZV + ei];
        unsigned int rec = 0xFFFFFFFFu;
        if ((unsigned)dst < NN && (unsigned)src < NN) {
            rec = ((unsigned)dst << 16) | (unsigned)src;
            atomicAdd(&lh[dst >> 8], 1u);
        }
        lrec[i] = rec;
    }
    __syncthreads();
    const unsigned int myslice = atomicAdd(&gcur[t], lh[t]);
    __syncthreads();
    lh[t] = myslice;
    __syncthreads();
    for (int i = t; i < EPW; i += 256) {
        const unsigned int rec = lrec[i];
        if (rec == 0xFFFFFFFFu) continue;
        const int e   = base + i;
        const int c   = e / NNZV;
        const int dst = (int)(rec >> 16);
        const int src = (int)(rec & 0xFFFFu);
        const int b   = dst >> 8;
        const unsigned int pos = atomicAdd(&lh[b], 1u);
        if (pos < RCAP)
            recs[(size_t)b * RCAP + pos] =
                ((unsigned)(dst & 255) << 18) | ((unsigned)c << 16) | (unsigned)src;
    }
}

__global__ __launch_bounds__(256) void cscatter2_kernel(const void* __restrict__ A,
                                                        unsigned int* __restrict__ gcur,
                                                        unsigned int* __restrict__ recs,
                                                        const int* __restrict__ flags) {
    __shared__ unsigned int lh[NBKT];
    __shared__ unsigned int lrec[EPW];
    if (flags[1]) cscat2_body<long long>((const long long*)A, gcur, recs, lh, lrec);
    else          cscat2_body<int>      ((const int*)A,       gcur, recs, lh, lrec);
}

// ---------------------------------------------------------------------------
// dfinal: one WG per bucket; computes its own obase (bscan folded in).
// ---------------------------------------------------------------------------
__global__ __launch_bounds__(256) void dfinal_kernel(const unsigned int* __restrict__ gcur,
                                                     const unsigned int* __restrict__ recs,
                                                     unsigned short* __restrict__ edge_src,
                                                     int* __restrict__ offs,
                                                     int* __restrict__ cnt) {
    __shared__ unsigned int scnt[1024], soff[1024];
    __shared__ unsigned int ts[256], red[256];
    const int b = blockIdx.x, t = threadIdx.x;
    red[t] = (t < b) ? gcur[t] : 0u;
    __syncthreads();
    for (int off = 128; off >= 1; off >>= 1) {
        if (t < off) red[t] += red[t + off];
        __syncthreads();
    }
    const unsigned int obase = red[0];
    int n = (int)gcur[b];
    if (n > RCAP) n = RCAP;
    const size_t rbase = (size_t)b * RCAP;
    for (int j = t; j < 1024; j += 256) scnt[j] = 0;
    __syncthreads();
    for (int i = t; i < n; i += 256) {
        const unsigned int r = recs[rbase + i];
        const int seg = (int)(((r >> 18) & 255u) * 4u + ((r >> 16) & 3u));
        atomicAdd(&scnt[seg], 1u);
    }
    __syncthreads();
    {
        const int j0 = t * 4;
        unsigned int v0 = scnt[j0], v1 = scnt[j0 + 1], v2 = scnt[j0 + 2], v3 = scnt[j0 + 3];
        unsigned int s = v0 + v1 + v2 + v3;
        ts[t] = s;
        __syncthreads();
        for (int off = 1; off < 256; off <<= 1) {
            unsigned int val = (t >= off) ? ts[t - off] : 0;
            __syncthreads();
            ts[t] += val;
            __syncthreads();
        }
        unsigned int ex = ts[t] - s;
        soff[j0] = ex; soff[j0 + 1] = ex + v0;
        soff[j0 + 2] = ex + v0 + v1; soff[j0 + 3] = ex + v0 + v1 + v2;
    }
    __syncthreads();
    for (int j = t; j < 1024; j += 256) {
        const int dst = b * 256 + (j >> 2);
        if (dst < NN) {
            offs[b * 1024 + j] = (int)(obase + soff[j]);
            cnt [b * 1024 + j] = (int)scnt[j];
        }
    }
    __syncthreads();
    for (int i = t; i < n; i += 256) {
        const unsigned int r = recs[rbase + i];
        const int seg = (int)(((r >> 18) & 255u) * 4u + ((r >> 16) & 3u));
        const unsigned int pos = atomicAdd(&soff[seg], 1u);
        edge_src[obase + pos] = (unsigned short)(r & 0xFFFFu);
    }
}

// ---------------------------------------------------------------------------
// gather: block = 4 dsts; wave c handles its category for all 4.
// Seg params for all 4 dsts hoisted (8 independent loads in flight).
// ---------------------------------------------------------------------------
__global__ __launch_bounds__(256) void gather_kernel(const unsigned short* __restrict__ edge_src,
                                                     const int* __restrict__ offs,
                                                     const int* __restrict__ cnt,
                                                     const unsigned short* __restrict__ XW,
                                                     unsigned short* __restrict__ H) {
    const int t    = threadIdx.x;
    const int c    = t >> 6;
    const int lane = t & 63;
    const int k    = lane >> 4;
    const int g4   = (lane & 15) * 4;
    const int d0   = blockIdx.x * 4;
    const unsigned short* xwc = XW + (size_t)c * NN * 64;
    int beg[4], num[4];
    #pragma unroll
    for (int dd = 0; dd < 4; ++dd) {
        const int seg = (d0 + dd) * 4 + c;
        beg[dd] = offs[seg];
        num[dd] = cnt[seg];
    }
    #pragma unroll
    for (int dd = 0; dd < 4; ++dd) {
        const int dst = d0 + dd;
        const int n   = num[dd];
        const unsigned short* ep = edge_src + beg[dd];
        float a0 = 0.f, a1 = 0.f, a2 = 0.f, a3 = 0.f;
        int e0 = 0;
        for (; e0 + 8 <= n; e0 += 8) {
            const int sa = ep[e0 + k];
            const int sb = ep[e0 + 4 + k];
            const ushort4 va = *(const ushort4*)(xwc + (size_t)sa * 64 + g4);
            const ushort4 vb = *(const ushort4*)(xwc + (size_t)sb * 64 + g4);
            a0 += bfu2f(va.x) + bfu2f(vb.x);
            a1 += bfu2f(va.y) + bfu2f(vb.y);
            a2 += bfu2f(va.z) + bfu2f(vb.z);
            a3 += bfu2f(va.w) + bfu2f(vb.w);
        }
        {
            const int ea = e0 + k;
            const int eb = e0 + 4 + k;
            if (ea < n) {
                const ushort4 v = *(const ushort4*)(xwc + (size_t)ep[ea] * 64 + g4);
                a0 += bfu2f(v.x); a1 += bfu2f(v.y); a2 += bfu2f(v.z); a3 += bfu2f(v.w);
            }
            if (eb < n) {
                const ushort4 v = *(const ushort4*)(xwc + (size_t)ep[eb] * 64 + g4);
                a0 += bfu2f(v.x); a1 += bfu2f(v.y); a2 += bfu2f(v.z); a3 += bfu2f(v.w);
            }
        }
        a0 += __shfl_xor(a0, 16, 64); a0 += __shfl_xor(a0, 32, 64);
        a1 += __shfl_xor(a1, 16, 64); a1 += __shfl_xor(a1, 32, 64);
        a2 += __shfl_xor(a2, 16, 64); a2 += __shfl_xor(a2, 32, 64);
        a3 += __shfl_xor(a3, 16, 64); a3 += __shfl_xor(a3, 32, 64);
        if (k == 0) {
            ushort4 o;
            o.x = tobits(a0); o.y = tobits(a1); o.z = tobits(a2); o.w = tobits(a3);
            *(ushort4*)(H + (size_t)dst * 256 + c * 64 + g4) = o;
        }
    }
}

// ---------------------------------------------------------------------------
// l0_mfma: h = H @ W0 + b0 (M=50000 K=256 N=128) + fused BN partial sums.
// Epilogue: LDS-transposed tile -> coalesced ushort8 stores.
// ---------------------------------------------------------------------------
__global__ __launch_bounds__(256) void l0_mfma(const unsigned short* __restrict__ Hg,
                                               const unsigned short* __restrict__ Wb,
                                               const float* __restrict__ bias0,
                                               unsigned short* __restrict__ hO,
                                               float* __restrict__ stats) {
    __shared__ unsigned short Hs[64 * 264];   // staged H (stride 264), then out tile (stride 136)
    __shared__ float psum[128], psq[128];
    const int t = threadIdx.x;
    const int n0 = blockIdx.x * 64;
    #pragma unroll
    for (int i = 0; i < 16; ++i) {
        const int r = (t >> 6) + i * 4;
        const int k = (t & 63) * 4;
        const int row = n0 + r;
        ushort4 v = make_ushort4(0, 0, 0, 0);
        if (row < NN) v = *(const ushort4*)(Hg + (size_t)row * 256 + k);
        *(ushort4*)(&Hs[r * 264 + k]) = v;
    }
    if (t < 128) { psum[t] = 0.f; psq[t] = 0.f; }
    __syncthreads();
    const int w = t >> 6, lane = t & 63;
    const int q = lane >> 4, cI = lane & 15;
    f32x4 acc[8];
    #pragma unroll
    for (int i = 0; i < 8; ++i) acc[i] = (f32x4){0.f, 0.f, 0.f, 0.f};
    const unsigned short* arow = &Hs[(w * 16 + cI) * 264 + q * 8];
    #pragma unroll
    for (int k0 = 0; k0 < 8; ++k0) {
        short8 a = *(const short8*)(arow + k0 * 32);
        #pragma unroll
        for (int t8 = 0; t8 < 8; ++t8) {
            short8 b = *(const short8*)(Wb + ((size_t)(k0 * 8 + t8) * 64 + lane) * 8);
            acc[t8] = __builtin_amdgcn_mfma_f32_16x16x32_bf16(a, b, acc[t8], 0, 0, 0);
        }
    }
    __syncthreads();   // done reading staged H
    const int rloc  = w * 16 + q * 4;
    const int rbase = n0 + rloc;
    #pragma unroll
    for (int t8 = 0; t8 < 8; ++t8) {
        const int col = t8 * 16 + cI;
        const float bc = bias0[col];
        float s = 0.f, qq = 0.f;
        #pragma unroll
        for (int r = 0; r < 4; ++r) {
            float v = acc[t8][r] + bc;
            Hs[(rloc + r) * 136 + col] = tobits(v);
            if (rbase + r >= NN) v = 0.f;
            s += v; qq += v * v;
        }
        s  += __shfl_xor(s, 16, 64);  s  += __shfl_xor(s, 32, 64);
        qq += __shfl_xor(qq, 16, 64); qq += __shfl_xor(qq, 32, 64);
        if (q == 0) { atomicAdd(&psum[col], s); atomicAdd(&psq[col], qq); }
    }
    __syncthreads();
    if (t < 128) { atomicAdd(&stats[t], psum[t]); atomicAdd(&stats[128 + t], psq[t]); }
    // store: 64 rows x 128 cols bf16; chunk = 8 cols; 1024 chunks / 256 thr = 4 each
    #pragma unroll
    for (int i = 0; i < 4; ++i) {
        const int m    = t + i * 256;
        const int row  = m >> 4;
        const int col0 = (m & 15) * 8;
        const int grow = n0 + row;
        if (grow < NN) {
            *(ushort4*)(hO + (size_t)grow * 128 + col0)     = *(ushort4*)(&Hs[row * 136 + col0]);
            *(ushort4*)(hO + (size_t)grow * 128 + col0 + 4) = *(ushort4*)(&Hs[row * 136 + col0 + 4]);
        }
    }
}

// ---------------------------------------------------------------------------
// bn: fold stats into per-column affine
// ---------------------------------------------------------------------------
template<typename TF>
__device__ __forceinline__ void bn_body(const float* __restrict__ stats,
                                        const TF* __restrict__ gamma,
                                        const TF* __restrict__ beta,
                                        float* __restrict__ coef) {
    const int j = threadIdx.x;
    const float invN = 1.0f / (float)NN;
    const float mean = stats[j] * invN;
    const float var  = stats[128 + j] * invN - mean * mean;
    const float inv  = rsqrtf(var + 1e-5f);
    const float a = cvt(gamma[j]) * inv;
    const float b = cvt(beta[j]) - mean * a;
    coef[j] = a;
    coef[128 + j] = b;
}

__global__ void bn_kernel(const float* __restrict__ stats,
                          const void* __restrict__ gamma,
                          const void* __restrict__ beta,
                          float* __restrict__ coef,
                          const int* __restrict__ flags) {
    if (flags[0]) bn_body<float>(stats, (const float*)gamma, (const float*)beta, coef);
    else          bn_body<bf16> (stats, (const bf16*)gamma,  (const bf16*)beta,  coef);
}

// ---------------------------------------------------------------------------
// l1_mfma: out = elu(bn(h)) @ W1 + b1  (M=50000 K=128 N=64)
// Epilogue: LDS float tile -> coalesced float4 / ushort4 stores.
// ---------------------------------------------------------------------------
__global__ __launch_bounds__(256) void l1_mfma(const unsigned short* __restrict__ hg,
                                               const float* __restrict__ coef,
                                               const unsigned short* __restrict__ Wb1,
                                               const float* __restrict__ bias1,
                                               void* __restrict__ outv,
                                               const int* __restrict__ flags) {
    __shared__ unsigned short Es[64 * 136];   // staged input, then reused as float out tile
    const int t = threadIdx.x;
    const int n0 = blockIdx.x * 64;
    #pragma unroll
    for (int i = 0; i < 8; ++i) {
        const int r = (t >> 5) + i * 8;
        const int k = (t & 31) * 4;
        const int row = n0 + r;
        ushort4 o = make_ushort4(0, 0, 0, 0);
        if (row < NN) {
            ushort4 v = *(const ushort4*)(hg + (size_t)row * 128 + k);
            float f0 = coef[k + 0] * bfu2f(v.x) + coef[128 + k + 0];
            float f1 = coef[k + 1] * bfu2f(v.y) + coef[128 + k + 1];
            float f2 = coef[k + 2] * bfu2f(v.z) + coef[128 + k + 2];
            float f3 = coef[k + 3] * bfu2f(v.w) + coef[128 + k + 3];
            f0 = f0 > 0.f ? f0 : expm1f(f0);
            f1 = f1 > 0.f ? f1 : expm1f(f1);
            f2 = f2 > 0.f ? f2 : expm1f(f2);
            f3 = f3 > 0.f ? f3 : expm1f(f3);
            o.x = tobits(f0); o.y = tobits(f1); o.z = tobits(f2); o.w = tobits(f3);
        }
        *(ushort4*)(&Es[r * 136 + k]) = o;
    }
    __syncthreads();
    const int w = t >> 6, lane = t & 63;
    const int q = lane >> 4, cI = lane & 15;
    f32x4 acc[4];
    #pragma unroll
    for (int i = 0; i < 4; ++i) acc[i] = (f32x4){0.f, 0.f, 0.f, 0.f};
    const unsigned short* arow = &Es[(w * 16 + cI) * 136 + q * 8];
    #pragma unroll
    for (int k0 = 0; k0 < 4; ++k0) {
        short8 a = *(const short8*)(arow + k0 * 32);
        #pragma unroll
        for (int t4 = 0; t4 < 4; ++t4) {
            short8 b = *(const short8*)(Wb1 + ((size_t)(k0 * 4 + t4) * 64 + lane) * 8);
            acc[t4] = __builtin_amdgcn_mfma_f32_16x16x32_bf16(a, b, acc[t4], 0, 0, 0);
        }
    }
    __syncthreads();   // done reading staged input
    float* ot = (float*)Es;                   // 64 x 68 float tile (17.4 KB fits)
    const int rloc = w * 16 + q * 4;
    #pragma unroll
    for (int t4 = 0; t4 < 4; ++t4) {
        const int col = t4 * 16 + cI;
        const float bc = bias1[col];
        #pragma unroll
        for (int r = 0; r < 4; ++r)
            ot[(rloc + r) * 68 + col] = acc[t4][r] + bc;
    }
    __syncthreads();
    const int f32out = flags[0];
    // 64 rows x 64 cols; chunk = 4 cols; 1024 chunks / 256 thr = 4 each
    #pragma unroll
    for (int i = 0; i < 4; ++i) {
        const int m    = t + i * 256;
        const int row  = m >> 4;
        const int col0 = (m & 15) * 4;
        const int grow = n0 + row;
        if (grow >= NN) continue;
        const float f0 = ot[row * 68 + col0 + 0];
        const float f1 = ot[row * 68 + col0 + 1];
        const float f2 = ot[row * 68 + col0 + 2];
        const float f3 = ot[row * 68 + col0 + 3];
        if (f32out) {
            float4 o; o.x = f0; o.y = f1; o.z = f2; o.w = f3;
            *(float4*)((float*)outv + (size_t)grow * 64 + col0) = o;
        } else {
            ushort4 o;
            o.x = tobits(f0); o.y = tobits(f1); o.z = tobits(f2); o.w = tobits(f3);
            *(ushort4*)((unsigned short*)outv + (size_t)grow * 64 + col0) = o;
        }
    }
}

// ---------------------------------------------------------------------------
// Workspace layout: unchanged from round 8 (~82.6 MiB); ebase slot unused.
// ---------------------------------------------------------------------------
extern "C" void kernel_launch(void* const* d_in, const int* in_sizes, int n_in,
                              void* d_out, int out_size, void* d_ws, size_t ws_size,
                              hipStream_t stream) {
    const void* A     = d_in[0];
    const void* X     = d_in[1];
    const void* Ws    = d_in[2];
    const void* W0    = d_in[3];
    const void* b0    = d_in[4];
    const void* gamma = d_in[5];
    const void* beta  = d_in[6];
    const void* W1    = d_in[7];
    const void* b1    = d_in[8];

    char* ws = (char*)d_ws;
    unsigned short* XW       = (unsigned short*)(ws);
    unsigned short* H        = (unsigned short*)(ws + 25600000);
    unsigned short* h        = (unsigned short*)(ws + 51200000);
    unsigned int*   recs     = (unsigned int*)  (ws + 64000000);
    int*            offs     = (int*)           (ws + 78451712);
    int*            cnt      = (int*)           (ws + 79251712);
    unsigned short* edge_src = (unsigned short*)(ws + 80051712);
    float*          stats    = (float*)         (ws + 86451712);
    unsigned int*   gcur     = (unsigned int*)  (ws + 86452736);
    float*          coef     = (float*)         (ws + 86453760);
    int*            flags    = (int*)           (ws + 86454784);
    unsigned short* Wb       = (unsigned short*)(ws + 86455040);
    unsigned short* Wb1      = (unsigned short*)(ws + 86520576);
    unsigned short* Wbx      = (unsigned short*)(ws + 86536960);
    float*          bias0    = (float*)         (ws + 86569728);
    float*          bias1    = (float*)         (ws + 86570240);

    detect_kernel<<<1, 256, 0, stream>>>((const unsigned int*)X, (const unsigned int*)A, flags);
    hipMemsetAsync(stats, 0, 2048, stream);   // zero stats + gcur every call

    pack_kernel     <<<29, 256, 0, stream>>>(W0, W1, Ws, b0, b1, Wb, Wb1, Wbx, bias0, bias1, flags);
    xw_mfma         <<<NRB, 256, 0, stream>>>(X, Wbx, XW, flags);
    cscatter2_kernel<<<NWG, 256, 0, stream>>>(A, gcur, recs, flags);
    dfinal_kernel   <<<196, 256, 0, stream>>>(gcur, recs, edge_src, offs, cnt);
    gather_kernel   <<<12500, 256, 0, stream>>>(edge_src, offs, cnt, XW, H);
    l0_mfma         <<<NRB, 256, 0, stream>>>(H, Wb, bias0, h, stats);
    bn_kernel       <<<1, 128, 0, stream>>>(stats, gamma, beta, coef, flags);
    l1_mfma         <<<NRB, 256, 0, stream>>>(h, coef, Wb1, bias1, d_out, flags);
}

// Round 10
// 278.370 us; speedup vs baseline: 1.7150x; 1.0988x over previous
//
#include <hip/hip_runtime.h>
#include <hip/hip_bf16.h>

#define NN    50000
#define CC    4
#define NNZV  800000
#define TOTE  (CC * NNZV)          // 3,200,000 edges
#define NWG   1024                 // workgroups for cscatter range
#define EPW   (TOTE / NWG)         // 3125 edges per WG (exact)
#define NBKT  256                  // dst buckets (dst >> 8); 196 non-empty
#define RCAP  18432                // records per bucket region
#define NRB   782                  // ceil(50000/64) row blocks for dense stages

using bf16 = __hip_bfloat16;
typedef short short8 __attribute__((ext_vector_type(8)));
typedef float f32x4  __attribute__((ext_vector_type(4)));

__device__ __forceinline__ float bfu2f(unsigned short u) {
    union { unsigned int i; float f; } v;
    v.i = ((unsigned int)u) << 16;
    return v.f;
}
__device__ __forceinline__ float cvt(float x) { return x; }
__device__ __forceinline__ float cvt(bf16 x)  { return __bfloat162float(x); }
__device__ __forceinline__ unsigned short tobits(float x) {
    bf16 t = __float2bfloat16(x);
    return *(unsigned short*)&t;
}

__device__ __forceinline__ ushort4 load4bits(const float* X, size_t idx) {
    const float4 v = *(const float4*)(X + idx);
    ushort4 o;
    o.x = tobits(v.x); o.y = tobits(v.y); o.z = tobits(v.z); o.w = tobits(v.w);
    return o;
}
__device__ __forceinline__ ushort4 load4bits(const bf16* X, size_t idx) {
    return *(const ushort4*)((const unsigned short*)X + idx);
}

// ---------------------------------------------------------------------------
// Inline dtype detection (per-block preamble; logic proven rounds 2-9).
// f32f = 1 if float inputs are f32; i64f = 1 if A is int64.
// dcnt is a 2-int LDS scratch. Ends with all threads synced.
// ---------------------------------------------------------------------------
__device__ __forceinline__ void detect_flags(const unsigned int* __restrict__ Xw,
                                             const unsigned int* __restrict__ Aw,
                                             int* dcnt, int& f32f, int& i64f) {
    const int t = threadIdx.x, nthr = blockDim.x;
    if (t < 2) dcnt[t] = 0;
    __syncthreads();
    int c1 = 0;
    for (int i = t; i < 1024; i += nthr) {
        unsigned b = (Xw[i] >> 7) & 0xFF;
        if (b >= 118 && b <= 134) c1++;
    }
    if (c1) atomicAdd(&dcnt[0], c1);
    if (t < 128) { if (Aw[2 * t + 1] == 0) atomicAdd(&dcnt[1], 1); }
    __syncthreads();
    f32f = (dcnt[0] < 512) ? 1 : 0;
    i64f = (dcnt[1] >= 96) ? 1 : 0;
    __syncthreads();
}

// ---------------------------------------------------------------------------
// pack_kernel: B-operand fragment packing + f32 biases (proven layouts).
// Block 0 additionally zeroes stats[256]+gcur[256] (memset folded in).
// ---------------------------------------------------------------------------
template<typename TF>
__device__ __forceinline__ void pack_body(const TF* __restrict__ W0, const TF* __restrict__ W1,
                                          const TF* __restrict__ Ws, const TF* __restrict__ b0,
                                          const TF* __restrict__ b1,
                                          unsigned short* __restrict__ Wb,
                                          unsigned short* __restrict__ Wb1,
                                          unsigned short* __restrict__ Wbx,
                                          float* __restrict__ bias0, float* __restrict__ bias1,
                                          int trip) {
    const int lane = trip & 63;
    const int q = lane >> 4, cI = lane & 15;
    if (trip < 4096) {
        const int k0 = trip >> 9, t8 = (trip >> 6) & 7;
        #pragma unroll
        for (int j = 0; j < 8; ++j)
            Wb[(size_t)trip * 8 + j] =
                tobits(cvt(W0[(size_t)(k0 * 32 + q * 8 + j) * 128 + t8 * 16 + cI]));
    } else if (trip < 5120) {
        const int u = trip - 4096;
        const int k0 = u >> 8, t4 = (u >> 6) & 3;
        #pragma unroll
        for (int j = 0; j < 8; ++j)
            Wb1[(size_t)u * 8 + j] =
                tobits(cvt(W1[(size_t)(k0 * 32 + q * 8 + j) * 64 + t4 * 16 + cI]));
    } else if (trip < 7168) {
        const int u = trip - 5120;
        const int k0 = u >> 10, tn = (u >> 6) & 15;
        const int col = tn * 16 + cI, c = col >> 6, g = col & 63;
        #pragma unroll
        for (int j = 0; j < 8; ++j)
            Wbx[(size_t)u * 8 + j] =
                tobits(cvt(Ws[((size_t)c * 64 + k0 * 32 + q * 8 + j) * 64 + g]));
    } else if (trip < 7296) {
        bias0[trip - 7168] = cvt(b0[trip - 7168]);
    } else if (trip < 7360) {
        bias1[trip - 7296] = cvt(b1[trip - 7296]);
    }
}

__global__ __launch_bounds__(256) void pack_kernel(const void* X, const void* A,
                                                   const void* W0, const void* W1,
                                                   const void* Ws, const void* b0,
                                                   const void* b1,
                                                   unsigned short* Wb, unsigned short* Wb1,
                                                   unsigned short* Wbx,
                                                   float* bias0, float* bias1,
                                                   unsigned int* zero512) {
    __shared__ int dcnt[2];
    int f32f, i64f;
    detect_flags((const unsigned int*)X, (const unsigned int*)A, dcnt, f32f, i64f);
    const int t = threadIdx.x;
    if (blockIdx.x == 0) { zero512[t] = 0u; zero512[t + 256] = 0u; }
    const int trip = blockIdx.x * 256 + t;
    if (trip >= 7360) return;
    if (f32f) pack_body<float>((const float*)W0, (const float*)W1, (const float*)Ws,
                               (const float*)b0, (const float*)b1, Wb, Wb1, Wbx, bias0, bias1, trip);
    else      pack_body<bf16> ((const bf16*)W0, (const bf16*)W1, (const bf16*)Ws,
                               (const bf16*)b0, (const bf16*)b1, Wb, Wb1, Wbx, bias0, bias1, trip);
}

// ---------------------------------------------------------------------------
// fused_kernel: blocks [0,NWG) = cscatter2, blocks [NWG, NWG+NRB) = xw_mfma.
// Independent phases overlapped in one launch. Shared LDS buffer aliased.
// ---------------------------------------------------------------------------
template<typename TI>
__device__ __forceinline__ void cscat2_body(const TI* __restrict__ A,
                                            unsigned int* __restrict__ gcur,
                                            unsigned int* __restrict__ recs,
                                            unsigned int* lh, unsigned int* lrec) {
    const int w = blockIdx.x, t = threadIdx.x;
    lh[t] = 0;
    __syncthreads();
    const int base = w * EPW;
    for (int i = t; i < EPW; i += 256) {
        const int e  = base + i;
        const int c  = e / NNZV;
        const int ei = e - c * NNZV;
        const int dst = (int)A[(size_t)(c * 2 + 0) * NNZV + ei];
        const int src = (int)A[(size_t)(c * 2 + 1) * NNZV + ei];
        unsigned int rec = 0xFFFFFFFFu;
        if ((unsigned)dst < NN && (unsigned)src < NN) {
            rec = ((unsigned)dst << 16) | (unsigned)src;
            atomicAdd(&lh[dst >> 8], 1u);
        }
        lrec[i] = rec;
    }
    __syncthreads();
    const unsigned int myslice = atomicAdd(&gcur[t], lh[t]);
    __syncthreads();
    lh[t] = myslice;
    __syncthreads();
    for (int i = t; i < EPW; i += 256) {
        const unsigned int rec = lrec[i];
        if (rec == 0xFFFFFFFFu) continue;
        const int e   = base + i;
        const int c   = e / NNZV;
        const int dst = (int)(rec >> 16);
        const int src = (int)(rec & 0xFFFFu);
        const int b   = dst >> 8;
        const unsigned int pos = atomicAdd(&lh[b], 1u);
        if (pos < RCAP)
            recs[(size_t)b * RCAP + pos] =
                ((unsigned)(dst & 255) << 18) | ((unsigned)c << 16) | (unsigned)src;
    }
}

template<typename TF>
__device__ __forceinline__ void xw_stage(const TF* __restrict__ X, unsigned short* Xs,
                                         int n0, int t) {
    #pragma unroll
    for (int i = 0; i < 4; ++i) {
        const int r = (t >> 4) + i * 16;
        const int k = (t & 15) * 4;
        const int row = n0 + r;
        ushort4 o = make_ushort4(0, 0, 0, 0);
        if (row < NN) o = load4bits(X, (size_t)row * 64 + k);
        *(ushort4*)(&Xs[r * 80 + k]) = o;
    }
}

__device__ __forceinline__ void xw_body(const void* __restrict__ X, int f32f,
                                        const unsigned short* __restrict__ Wbx,
                                        unsigned short* __restrict__ XW,
                                        unsigned short* Xs, int bidx) {
    const int t = threadIdx.x, n0 = bidx * 64;
    if (f32f) xw_stage<float>((const float*)X, Xs, n0, t);
    else      xw_stage<bf16> ((const bf16*)X,  Xs, n0, t);
    __syncthreads();
    const int w = t >> 6, lane = t & 63;
    const int q = lane >> 4, cI = lane & 15;
    f32x4 acc[16];
    #pragma unroll
    for (int i = 0; i < 16; ++i) acc[i] = (f32x4){0.f, 0.f, 0.f, 0.f};
    const unsigned short* arow = &Xs[(w * 16 + cI) * 80 + q * 8];
    short8 a0 = *(const short8*)(arow);
    short8 a1 = *(const short8*)(arow + 32);
    #pragma unroll
    for (int tn = 0; tn < 16; ++tn) {
        short8 b = *(const short8*)(Wbx + ((size_t)tn * 64 + lane) * 8);
        acc[tn] = __builtin_amdgcn_mfma_f32_16x16x32_bf16(a0, b, acc[tn], 0, 0, 0);
    }
    #pragma unroll
    for (int tn = 0; tn < 16; ++tn) {
        short8 b = *(const short8*)(Wbx + ((size_t)(16 + tn) * 64 + lane) * 8);
        acc[tn] = __builtin_amdgcn_mfma_f32_16x16x32_bf16(a1, b, acc[tn], 0, 0, 0);
    }
    __syncthreads();
    const int rloc = w * 16 + q * 4;
    #pragma unroll
    for (int tn = 0; tn < 16; ++tn) {
        const int col = tn * 16 + cI;
        #pragma unroll
        for (int r = 0; r < 4; ++r)
            Xs[(rloc + r) * 264 + col] = tobits(acc[tn][r]);
    }
    __syncthreads();
    #pragma unroll
    for (int i = 0; i < 8; ++i) {
        const int m    = t + i * 256;
        const int row  = m >> 5;
        const int col0 = (m & 31) * 8;
        const int c    = col0 >> 6, g = col0 & 63;
        const int grow = n0 + row;
        if (grow < NN) {
            *(ushort4*)(XW + ((size_t)c * NN + grow) * 64 + g)     = *(ushort4*)(&Xs[row * 264 + col0]);
            *(ushort4*)(XW + ((size_t)c * NN + grow) * 64 + g + 4) = *(ushort4*)(&Xs[row * 264 + col0 + 4]);
        }
    }
}

__global__ __launch_bounds__(256) void fused_kernel(const void* __restrict__ X,
                                                    const void* __restrict__ A,
                                                    const unsigned short* __restrict__ Wbx,
                                                    unsigned short* __restrict__ XW,
                                                    unsigned int* __restrict__ gcur,
                                                    unsigned int* __restrict__ recs) {
    __shared__ unsigned short S[64 * 264];   // 33,792 B shared by both ranges
    __shared__ int dcnt[2];
    int f32f, i64f;
    detect_flags((const unsigned int*)X, (const unsigned int*)A, dcnt, f32f, i64f);
    if (blockIdx.x < NWG) {
        unsigned int* lh   = (unsigned int*)S;        // 256 u32
        unsigned int* lrec = (unsigned int*)S + 256;  // 3125 u32
        if (i64f) cscat2_body<long long>((const long long*)A, gcur, recs, lh, lrec);
        else      cscat2_body<int>      ((const int*)A,       gcur, recs, lh, lrec);
    } else {
        xw_body(X, f32f, Wbx, XW, S, blockIdx.x - NWG);
    }
}

// ---------------------------------------------------------------------------
// dfinal v2: 1024 threads/block, one block per bucket; records LDS-cached
// (single global read); obase self-computed; emits segd int2 (off,cnt).
// ---------------------------------------------------------------------------
__global__ __launch_bounds__(1024) void dfinal_kernel(const unsigned int* __restrict__ gcur,
                                                      const unsigned int* __restrict__ recs,
                                                      unsigned short* __restrict__ edge_src,
                                                      int2* __restrict__ segd) {
    __shared__ unsigned int lrec[RCAP];            // 73,728 B
    __shared__ unsigned int scnt[1024], soff[1024];
    __shared__ unsigned int ts[256], redv[256];
    const int b = blockIdx.x, t = threadIdx.x;
    if (t < 256) redv[t] = (t < b) ? gcur[t] : 0u;
    __syncthreads();
    for (int off = 128; off >= 1; off >>= 1) {
        if (t < off) redv[t] += redv[t + off];
        __syncthreads();
    }
    const unsigned int obase = redv[0];
    int n = (int)gcur[b];
    if (n > RCAP) n = RCAP;
    const size_t rbase = (size_t)b * RCAP;
    scnt[t] = 0;
    __syncthreads();
    for (int i = t; i < n; i += 1024) {
        const unsigned int r = recs[rbase + i];
        lrec[i] = r;
        const int seg = (int)(((r >> 18) & 255u) * 4u + ((r >> 16) & 3u));
        atomicAdd(&scnt[seg], 1u);
    }
    __syncthreads();
    // exclusive scan of scnt[1024] using threads t<256 (4 elems each)
    unsigned int v0 = 0, v1 = 0, v2 = 0, v3 = 0, s = 0;
    if (t < 256) {
        const int j0 = t * 4;
        v0 = scnt[j0]; v1 = scnt[j0 + 1]; v2 = scnt[j0 + 2]; v3 = scnt[j0 + 3];
        s = v0 + v1 + v2 + v3;
        ts[t] = s;
    }
    __syncthreads();
    for (int off = 1; off < 256; off <<= 1) {
        unsigned int val = 0;
        if (t < 256 && t >= off) val = ts[t - off];
        __syncthreads();
        if (t < 256) ts[t] += val;
        __syncthreads();
    }
    if (t < 256) {
        const int j0 = t * 4;
        unsigned int ex = ts[t] - s;
        soff[j0] = ex; soff[j0 + 1] = ex + v0;
        soff[j0 + 2] = ex + v0 + v1; soff[j0 + 3] = ex + v0 + v1 + v2;
    }
    __syncthreads();
    {
        const int dst = b * 256 + (t >> 2);
        if (dst < NN) {
            int2 o; o.x = (int)(obase + soff[t]); o.y = (int)scnt[t];
            segd[b * 1024 + t] = o;
        }
    }
    __syncthreads();
    for (int i = t; i < n; i += 1024) {
        const unsigned int r = lrec[i];
        const int seg = (int)(((r >> 18) & 255u) * 4u + ((r >> 16) & 3u));
        const unsigned int pos = atomicAdd(&soff[seg], 1u);
        edge_src[obase + pos] = (unsigned short)(r & 0xFFFFu);
    }
}

// ---------------------------------------------------------------------------
// gather: block = 4 dsts; wave c handles its category for all 4 (proven r8-9).
// segd int2 -> one load per segment.
// ---------------------------------------------------------------------------
__global__ __launch_bounds__(256) void gather_kernel(const unsigned short* __restrict__ edge_src,
                                                     const int2* __restrict__ segd,
                                                     const unsigned short* __restrict__ XW,
                                                     unsigned short* __restrict__ H) {
    const int t    = threadIdx.x;
    const int c    = t >> 6;
    const int lane = t & 63;
    const int k    = lane >> 4;
    const int g4   = (lane & 15) * 4;
    const int d0   = blockIdx.x * 4;
    const unsigned short* xwc = XW + (size_t)c * NN * 64;
    int2 sd[4];
    #pragma unroll
    for (int dd = 0; dd < 4; ++dd)
        sd[dd] = segd[(d0 + dd) * 4 + c];
    #pragma unroll
    for (int dd = 0; dd < 4; ++dd) {
        const int dst = d0 + dd;
        const int n   = sd[dd].y;
        const unsigned short* ep = edge_src + sd[dd].x;
        float a0 = 0.f, a1 = 0.f, a2 = 0.f, a3 = 0.f;
        int e0 = 0;
        for (; e0 + 8 <= n; e0 += 8) {
            const int sa = ep[e0 + k];
            const int sb = ep[e0 + 4 + k];
            const ushort4 va = *(const ushort4*)(xwc + (size_t)sa * 64 + g4);
            const ushort4 vb = *(const ushort4*)(xwc + (size_t)sb * 64 + g4);
            a0 += bfu2f(va.x) + bfu2f(vb.x);
            a1 += bfu2f(va.y) + bfu2f(vb.y);
            a2 += bfu2f(va.z) + bfu2f(vb.z);
            a3 += bfu2f(va.w) + bfu2f(vb.w);
        }
        {
            const int ea = e0 + k;
            const int eb = e0 + 4 + k;
            if (ea < n) {
                const ushort4 v = *(const ushort4*)(xwc + (size_t)ep[ea] * 64 + g4);
                a0 += bfu2f(v.x); a1 += bfu2f(v.y); a2 += bfu2f(v.z); a3 += bfu2f(v.w);
            }
            if (eb < n) {
                const ushort4 v = *(const ushort4*)(xwc + (size_t)ep[eb] * 64 + g4);
                a0 += bfu2f(v.x); a1 += bfu2f(v.y); a2 += bfu2f(v.z); a3 += bfu2f(v.w);
            }
        }
        a0 += __shfl_xor(a0, 16, 64); a0 += __shfl_xor(a0, 32, 64);
        a1 += __shfl_xor(a1, 16, 64); a1 += __shfl_xor(a1, 32, 64);
        a2 += __shfl_xor(a2, 16, 64); a2 += __shfl_xor(a2, 32, 64);
        a3 += __shfl_xor(a3, 16, 64); a3 += __shfl_xor(a3, 32, 64);
        if (k == 0) {
            ushort4 o;
            o.x = tobits(a0); o.y = tobits(a1); o.z = tobits(a2); o.w = tobits(a3);
            *(ushort4*)(H + (size_t)dst * 256 + c * 64 + g4) = o;
        }
    }
}

// ---------------------------------------------------------------------------
// l0_mfma: h = H @ W0 + b0 + fused BN partial sums (proven r9).
// ---------------------------------------------------------------------------
__global__ __launch_bounds__(256) void l0_mfma(const unsigned short* __restrict__ Hg,
                                               const unsigned short* __restrict__ Wb,
                                               const float* __restrict__ bias0,
                                               unsigned short* __restrict__ hO,
                                               float* __restrict__ stats) {
    __shared__ unsigned short Hs[64 * 264];
    __shared__ float psum[128], psq[128];
    const int t = threadIdx.x;
    const int n0 = blockIdx.x * 64;
    #pragma unroll
    for (int i = 0; i < 16; ++i) {
        const int r = (t >> 6) + i * 4;
        const int k = (t & 63) * 4;
        const int row = n0 + r;
        ushort4 v = make_ushort4(0, 0, 0, 0);
        if (row < NN) v = *(const ushort4*)(Hg + (size_t)row * 256 + k);
        *(ushort4*)(&Hs[r * 264 + k]) = v;
    }
    if (t < 128) { psum[t] = 0.f; psq[t] = 0.f; }
    __syncthreads();
    const int w = t >> 6, lane = t & 63;
    const int q = lane >> 4, cI = lane & 15;
    f32x4 acc[8];
    #pragma unroll
    for (int i = 0; i < 8; ++i) acc[i] = (f32x4){0.f, 0.f, 0.f, 0.f};
    const unsigned short* arow = &Hs[(w * 16 + cI) * 264 + q * 8];
    #pragma unroll
    for (int k0 = 0; k0 < 8; ++k0) {
        short8 a = *(const short8*)(arow + k0 * 32);
        #pragma unroll
        for (int t8 = 0; t8 < 8; ++t8) {
            short8 b = *(const short8*)(Wb + ((size_t)(k0 * 8 + t8) * 64 + lane) * 8);
            acc[t8] = __builtin_amdgcn_mfma_f32_16x16x32_bf16(a, b, acc[t8], 0, 0, 0);
        }
    }
    __syncthreads();
    const int rloc  = w * 16 + q * 4;
    const int rbase = n0 + rloc;
    #pragma unroll
    for (int t8 = 0; t8 < 8; ++t8) {
        const int col = t8 * 16 + cI;
        const float bc = bias0[col];
        float s = 0.f, qq = 0.f;
        #pragma unroll
        for (int r = 0; r < 4; ++r) {
            float v = acc[t8][r] + bc;
            Hs[(rloc + r) * 136 + col] = tobits(v);
            if (rbase + r >= NN) v = 0.f;
            s += v; qq += v * v;
        }
        s  += __shfl_xor(s, 16, 64);  s  += __shfl_xor(s, 32, 64);
        qq += __shfl_xor(qq, 16, 64); qq += __shfl_xor(qq, 32, 64);
        if (q == 0) { atomicAdd(&psum[col], s); atomicAdd(&psq[col], qq); }
    }
    __syncthreads();
    if (t < 128) { atomicAdd(&stats[t], psum[t]); atomicAdd(&stats[128 + t], psq[t]); }
    #pragma unroll
    for (int i = 0; i < 4; ++i) {
        const int m    = t + i * 256;
        const int row  = m >> 4;
        const int col0 = (m & 15) * 8;
        const int grow = n0 + row;
        if (grow < NN) {
            *(ushort4*)(hO + (size_t)grow * 128 + col0)     = *(ushort4*)(&Hs[row * 136 + col0]);
            *(ushort4*)(hO + (size_t)grow * 128 + col0 + 4) = *(ushort4*)(&Hs[row * 136 + col0 + 4]);
        }
    }
}

// ---------------------------------------------------------------------------
// l1_mfma: out = elu(bn(h)) @ W1 + b1; bn-coef computed in preamble (bn fused).
// ---------------------------------------------------------------------------
__global__ __launch_bounds__(256) void l1_mfma(const void* __restrict__ X,
                                               const void* __restrict__ A,
                                               const unsigned short* __restrict__ hg,
                                               const float* __restrict__ stats,
                                               const void* __restrict__ gamma,
                                               const void* __restrict__ beta,
                                               const unsigned short* __restrict__ Wb1,
                                               const float* __restrict__ bias1,
                                               void* __restrict__ outv) {
    __shared__ unsigned short Es[64 * 136];
    __shared__ float coefL[256];
    __shared__ int dcnt[2];
    int f32f, i64f;
    detect_flags((const unsigned int*)X, (const unsigned int*)A, dcnt, f32f, i64f);
    const int t = threadIdx.x;
    if (t < 128) {
        const float invN = 1.0f / (float)NN;
        const float mean = stats[t] * invN;
        const float var  = stats[128 + t] * invN - mean * mean;
        const float inv  = rsqrtf(var + 1e-5f);
        const float ga = f32f ? ((const float*)gamma)[t] : cvt(((const bf16*)gamma)[t]);
        const float be = f32f ? ((const float*)beta)[t]  : cvt(((const bf16*)beta)[t]);
        const float a = ga * inv;
        coefL[t] = a;
        coefL[128 + t] = be - mean * a;
    }
    __syncthreads();
    const int n0 = blockIdx.x * 64;
    #pragma unroll
    for (int i = 0; i < 8; ++i) {
        const int r = (t >> 5) + i * 8;
        const int k = (t & 31) * 4;
        const int row = n0 + r;
        ushort4 o = make_ushort4(0, 0, 0, 0);
        if (row < NN) {
            ushort4 v = *(const ushort4*)(hg + (size_t)row * 128 + k);
            float f0 = coefL[k + 0] * bfu2f(v.x) + coefL[128 + k + 0];
            float f1 = coefL[k + 1] * bfu2f(v.y) + coefL[128 + k + 1];
            float f2 = coefL[k + 2] * bfu2f(v.z) + coefL[128 + k + 2];
            float f3 = coefL[k + 3] * bfu2f(v.w) + coefL[128 + k + 3];
            f0 = f0 > 0.f ? f0 : expm1f(f0);
            f1 = f1 > 0.f ? f1 : expm1f(f1);
            f2 = f2 > 0.f ? f2 : expm1f(f2);
            f3 = f3 > 0.f ? f3 : expm1f(f3);
            o.x = tobits(f0); o.y = tobits(f1); o.z = tobits(f2); o.w = tobits(f3);
        }
        *(ushort4*)(&Es[r * 136 + k]) = o;
    }
    __syncthreads();
    const int w = t >> 6, lane = t & 63;
    const int q = lane >> 4, cI = lane & 15;
    f32x4 acc[4];
    #pragma unroll
    for (int i = 0; i < 4; ++i) acc[i] = (f32x4){0.f, 0.f, 0.f, 0.f};
    const unsigned short* arow = &Es[(w * 16 + cI) * 136 + q * 8];
    #pragma unroll
    for (int k0 = 0; k0 < 4; ++k0) {
        short8 a = *(const short8*)(arow + k0 * 32);
        #pragma unroll
        for (int t4 = 0; t4 < 4; ++t4) {
            short8 b = *(const short8*)(Wb1 + ((size_t)(k0 * 4 + t4) * 64 + lane) * 8);
            acc[t4] = __builtin_amdgcn_mfma_f32_16x16x32_bf16(a, b, acc[t4], 0, 0, 0);
        }
    }
    __syncthreads();
    float* ot = (float*)Es;                   // 64 x 68 float tile
    const int rloc = w * 16 + q * 4;
    #pragma unroll
    for (int t4 = 0; t4 < 4; ++t4) {
        const int col = t4 * 16 + cI;
        const float bc = bias1[col];
        #pragma unroll
        for (int r = 0; r < 4; ++r)
            ot[(rloc + r) * 68 + col] = acc[t4][r] + bc;
    }
    __syncthreads();
    #pragma unroll
    for (int i = 0; i < 4; ++i) {
        const int m    = t + i * 256;
        const int row  = m >> 4;
        const int col0 = (m & 15) * 4;
        const int grow = n0 + row;
        if (grow >= NN) continue;
        const float f0 = ot[row * 68 + col0 + 0];
        const float f1 = ot[row * 68 + col0 + 1];
        const float f2 = ot[row * 68 + col0 + 2];
        const float f3 = ot[row * 68 + col0 + 3];
        if (f32f) {
            float4 o; o.x = f0; o.y = f1; o.z = f2; o.w = f3;
            *(float4*)((float*)outv + (size_t)grow * 64 + col0) = o;
        } else {
            ushort4 o;
            o.x = tobits(f0); o.y = tobits(f1); o.z = tobits(f2); o.w = tobits(f3);
            *(ushort4*)((unsigned short*)outv + (size_t)grow * 64 + col0) = o;
        }
    }
}

// ---------------------------------------------------------------------------
// Workspace layout (bytes):
//   XW       : [C,N,64] bf16   @ 0            25,600,000
//   H        : [N,256]  bf16   @ 25,600,000   25,600,000
//   h        : [N,128]  bf16   @ 51,200,000   12,800,000
//   recs     : [196*RCAP] u32  @ 64,000,000   14,450,688
//   segd     : [200000] int2   @ 78,451,712    1,600,000
//   edge_src : [3.2M] u16      @ 80,051,712    6,400,000
//   stats    : [256] f32       @ 86,451,712        1,024  -- zeroed by pack
//   gcur     : [256] u32       @ 86,452,736        1,024  -- zeroed by pack
//   Wb       : u16             @ 86,455,040       65,536
//   Wb1      : u16             @ 86,520,576       16,384
//   Wbx      : u16             @ 86,536,960       32,768
//   bias0    : f32[128]        @ 86,569,728          512
//   bias1    : f32[64]         @ 86,570,240          256
// total 86,570,496 B (~82.6 MiB)
// ---------------------------------------------------------------------------
extern "C" void kernel_launch(void* const* d_in, const int* in_sizes, int n_in,
                              void* d_out, int out_size, void* d_ws, size_t ws_size,
                              hipStream_t stream) {
    const void* A     = d_in[0];
    const void* X     = d_in[1];
    const void* Ws    = d_in[2];
    const void* W0    = d_in[3];
    const void* b0    = d_in[4];
    const void* gamma = d_in[5];
    const void* beta  = d_in[6];
    const void* W1    = d_in[7];
    const void* b1    = d_in[8];

    char* ws = (char*)d_ws;
    unsigned short* XW       = (unsigned short*)(ws);
    unsigned short* H        = (unsigned short*)(ws + 25600000);
    unsigned short* h        = (unsigned short*)(ws + 51200000);
    unsigned int*   recs     = (unsigned int*)  (ws + 64000000);
    int2*           segd     = (int2*)          (ws + 78451712);
    unsigned short* edge_src = (unsigned short*)(ws + 80051712);
    float*          stats    = (float*)         (ws + 86451712);
    unsigned int*   gcur     = (unsigned int*)  (ws + 86452736);
    unsigned short* Wb       = (unsigned short*)(ws + 86455040);
    unsigned short* Wb1      = (unsigned short*)(ws + 86520576);
    unsigned short* Wbx      = (unsigned short*)(ws + 86536960);
    float*          bias0    = (float*)         (ws + 86569728);
    float*          bias1    = (float*)         (ws + 86570240);

    pack_kernel  <<<29, 256, 0, stream>>>(X, A, W0, W1, Ws, b0, b1,
                                          Wb, Wb1, Wbx, bias0, bias1,
                                          (unsigned int*)stats /* zeroes stats+gcur */);
    fused_kernel <<<NWG + NRB, 256, 0, stream>>>(X, A, Wbx, XW, gcur, recs);
    dfinal_kernel<<<196, 1024, 0, stream>>>(gcur, recs, edge_src, segd);
    gather_kernel<<<12500, 256, 0, stream>>>(edge_src, segd, XW, H);
    l0_mfma      <<<NRB, 256, 0, stream>>>(H, Wb, bias0, h, stats);
    l1_mfma      <<<NRB, 256, 0, stream>>>(X, A, h, stats, gamma, beta, Wb1, bias1, d_out);
}